// Round 3
// baseline (178.475 us; speedup 1.0000x reference)
//
#include <hip/hip_runtime.h>
#include <math.h>
#include <stdint.h>

#define NIMG   8
#define NA     30000      // H*W*A = 100*100*3
#define PRE_N  2000
#define POST_N 1000
#define NMS_TH 0.7f
#define DCLIP  4.135166556742356f   // log(1000/16)
#define IMGF   1600.0f
#define IMGM1  1599.0f
#define CAND_MAX 4096
#define BIG_BIN  64       // bins larger than this get a 2nd-level radix pass

// ws layout (floats): boxes [8][2000][4] @0, scores [8][2000] @64000,
//   valid(int) [8][2000] @80000, mask(u64) [8][2000][32] @96000.

// ---------------------------------------------------------------------------
// decode + store helper (verified math, unchanged from R1/R2)
// ---------------------------------------------------------------------------
__device__ __forceinline__ void decode_store(
    uint64_t key, unsigned int rank, int n, const float* __restrict__ breg,
    float* __restrict__ wsBoxes, float* __restrict__ wsScores,
    int* __restrict__ wsValid)
{
    unsigned int idx = (unsigned int)key;
    unsigned int k   = ~((unsigned int)(key >> 32));
    unsigned int u   = (k & 0x80000000u) ? (k & 0x7fffffffu) : ~k;
    float logit = __uint_as_float(u);
    float score = 1.0f / (1.0f + expf(-logit));

    int a = idx % 3, t = idx / 3, w = t % 100, h = t / 100;
    const float* bp = breg + n*120000 + (a*4)*10000 + t;
    float dx = bp[0], dy = bp[10000], dw = bp[20000], dh = bp[30000];

    float half = (a == 0) ? 32.0f : ((a == 1) ? 64.0f : 128.0f);
    float cx = w * 16.0f + 8.0f, cy = h * 16.0f + 8.0f;
    float x1 = cx - half, y1 = cy - half, x2 = cx + half, y2 = cy + half;
    float wd = x2 - x1 + 1.0f, hg = y2 - y1 + 1.0f;
    float cxr = x1 + 0.5f * wd, cyr = y1 + 0.5f * hg;
    dw = fminf(dw, DCLIP); dh = fminf(dh, DCLIP);
    float pcx = dx * wd + cxr, pcy = dy * hg + cyr;
    float pw = expf(dw) * wd, ph = expf(dh) * hg;
    float px1 = pcx - 0.5f * pw, py1 = pcy - 0.5f * ph;
    float px2 = pcx + 0.5f * pw - 1.0f, py2 = pcy + 0.5f * ph - 1.0f;
    px1 = fminf(fmaxf(px1, 0.0f), IMGM1);
    px2 = fminf(fmaxf(px2, 0.0f), IMGM1);
    py1 = fminf(fmaxf(py1, 0.0f), IMGM1);
    py2 = fminf(fmaxf(py2, 0.0f), IMGM1);
    float wss = px2 - px1 + 1.0f, hss = py2 - py1 + 1.0f;
    float xc = px1 + wss * 0.5f, yc = py1 + hss * 0.5f;
    int valid = (wss >= 0.0f) && (hss >= 0.0f) && (xc < IMGF) && (yc < IMGF);

    ((float4*)wsBoxes)[n * PRE_N + (int)rank] = make_float4(px1, py1, px2, py2);
    wsScores[n * PRE_N + (int)rank] = score;
    wsValid [n * PRE_N + (int)rank] = valid;
}

// ---------------------------------------------------------------------------
// Kernel AB: fused hist + suffix-sum + bin-grouped rank + decode.
// R3 fix: dense bins (>BIG_BIN elems) were rank-scanned by EVERY wave whose
// slots fell in them (~28k broadcast ds_read_b64 on one CU => ~40us, LDS-
// throughput-bound at VALUBusy ~1%). Now each large bin gets a 2nd-level
// radix pass on key bits 19:8 (hist2/sufx2/grp2): rank = gbeg + sufx2[sb] +
// tiny within-sub-bin scan (~1.3 elems avg). Small bins keep the 8-wide scan.
// ---------------------------------------------------------------------------
__global__ __launch_bounds__(1024) void topk_decode(
    const float* __restrict__ obj, const float* __restrict__ breg,
    float* __restrict__ wsBoxes, float* __restrict__ wsScores,
    int* __restrict__ wsValid)
{
    const int n    = blockIdx.x;
    const int tid  = threadIdx.x;
    const int lane = tid & 63;
    const int wid  = tid >> 6;

    __shared__ unsigned int   hist[4096];     // pass1: counts; pass2: arrival ctrs
    __shared__ unsigned short sufx[4096];     // #elems in bins strictly above b
    __shared__ uint64_t       grp[CAND_MAX];  // bin-grouped candidate keys (32 KB)
    __shared__ unsigned int   hist2[4096];    // 2nd-level counts / arrival ctrs
    __shared__ unsigned short sufx2[4096];    // 2nd-level suffix sums
    __shared__ uint64_t       grp2[CAND_MAX]; // sub-bin-grouped keys (32 KB)
    __shared__ unsigned int   wsum[16];
    __shared__ unsigned int   sbstar;
    __shared__ int            lbin[64];       // large-bin list
    __shared__ unsigned int   lbcnt;

    for (int b = tid; b < 4096; b += 1024) hist[b] = 0u;
    if (tid == 0) lbcnt = 0u;
    __syncthreads();

    const float* objn = obj + n * NA;

    // ---- pass 1: 12-bit-key histogram --------------------------------------
    for (int j = tid; j < NA; j += 1024) {
        unsigned int u = __float_as_uint(objn[j]);
        unsigned int k = (u & 0x80000000u) ? ~u : (u | 0x80000000u);
        atomicAdd(&hist[k >> 20], 1u);
    }
    __syncthreads();

    // ---- suffix-scan (verified structure) ----------------------------------
    unsigned int c0 = hist[tid*4+0], c1 = hist[tid*4+1],
                 c2 = hist[tid*4+2], c3 = hist[tid*4+3];
    unsigned int p = c0 + c1 + c2 + c3;
    unsigned int s = p;
    #pragma unroll
    for (int off = 1; off < 64; off <<= 1) {
        unsigned int v = __shfl_down(s, off);
        if (lane + off < 64) s += v;
    }
    if (lane == 0) wsum[wid] = s;
    __syncthreads();
    unsigned int wafter = 0;
    for (int w = wid + 1; w < 16; ++w) wafter += wsum[w];
    unsigned int after = (s - p) + wafter;   // elems in bins > 4t+3
    {
        unsigned int S3 = after + c3;        // elems in bins > 4t+2
        unsigned int S2 = S3 + c2;           // elems in bins > 4t+1
        unsigned int S1 = S2 + c1;           // elems in bins > 4t+0
        unsigned int S0 = S1 + c0;
        if (S3 >= PRE_N && after < PRE_N) { sbstar = tid*4+3; }
        if (S2 >= PRE_N && S3    < PRE_N) { sbstar = tid*4+2; }
        if (S1 >= PRE_N && S2    < PRE_N) { sbstar = tid*4+1; }
        if (S0 >= PRE_N && S1    < PRE_N) { sbstar = tid*4+0; }
        sufx[tid*4+0] = (unsigned short)S1;  // values <= 30000, fits u16
        sufx[tid*4+1] = (unsigned short)S2;
        sufx[tid*4+2] = (unsigned short)S3;
        sufx[tid*4+3] = (unsigned short)after;
    }
    __syncthreads();
    const unsigned int bstar = sbstar;

    // ---- zero own bins (arrival ctrs) + build large-bin list ---------------
    {
        const unsigned int cc[4] = {c0, c1, c2, c3};
        #pragma unroll
        for (int q = 0; q < 4; ++q) {
            const unsigned int b = (unsigned int)(tid*4 + q);
            hist[b] = 0u;
            if (b >= bstar && cc[q] > (unsigned int)BIG_BIN) {
                unsigned int pos = atomicAdd(&lbcnt, 1u);
                if (pos < 64u) lbin[pos] = (int)b;
            }
        }
    }
    __syncthreads();

    // ---- pass 2: bin-grouped placement into LDS ----------------------------
    for (int j = tid; j < NA; j += 1024) {
        unsigned int u = __float_as_uint(objn[j]);
        unsigned int k = (u & 0x80000000u) ? ~u : (u | 0x80000000u);
        unsigned int b = k >> 20;
        if (b < bstar) continue;
        int a = j / 10000, t = j - a * 10000;
        uint64_t key = (((uint64_t)(~k)) << 32) | (unsigned int)(t * 3 + a);
        unsigned int slot = (unsigned int)sufx[b] + atomicAdd(&hist[b], 1u);
        if (slot < CAND_MAX) grp[slot] = key;
    }
    __syncthreads();

    const unsigned int total =
        min((unsigned int)sufx[bstar] + hist[bstar], (unsigned int)CAND_MAX);
    const unsigned int nlb = min(lbcnt, 64u);

    // ---- 2nd-level radix passes for large bins -----------------------------
    for (unsigned int li = 0; li < nlb; ++li) {
        const unsigned int L    = (unsigned int)lbin[li];
        const unsigned int gbeg = sufx[L];
        const unsigned int gend = min(gbeg + hist[L], (unsigned int)CAND_MAX);
        const unsigned int m    = gend - gbeg;

        for (int sb = tid; sb < 4096; sb += 1024) hist2[sb] = 0u;
        __syncthreads();

        for (unsigned int s2 = gbeg + tid; s2 < gend; s2 += 1024) {
            unsigned int k = ~((unsigned int)(grp[s2] >> 32));
            atomicAdd(&hist2[(k >> 8) & 0xfffu], 1u);
        }
        __syncthreads();

        {   // suffix scan of hist2 -> sufx2, then zero own bins (arrival ctrs)
            unsigned int d0 = hist2[tid*4+0], d1 = hist2[tid*4+1],
                         d2 = hist2[tid*4+2], d3 = hist2[tid*4+3];
            unsigned int pp = d0 + d1 + d2 + d3;
            unsigned int ss = pp;
            #pragma unroll
            for (int off = 1; off < 64; off <<= 1) {
                unsigned int v = __shfl_down(ss, off);
                if (lane + off < 64) ss += v;
            }
            if (lane == 0) wsum[wid] = ss;
            __syncthreads();
            unsigned int wa = 0;
            for (int w = wid + 1; w < 16; ++w) wa += wsum[w];
            unsigned int af = (ss - pp) + wa;
            sufx2[tid*4+0] = (unsigned short)(af + d3 + d2 + d1);
            sufx2[tid*4+1] = (unsigned short)(af + d3 + d2);
            sufx2[tid*4+2] = (unsigned short)(af + d3);
            sufx2[tid*4+3] = (unsigned short)af;
            hist2[tid*4+0] = 0u; hist2[tid*4+1] = 0u;
            hist2[tid*4+2] = 0u; hist2[tid*4+3] = 0u;
        }
        __syncthreads();

        for (unsigned int s2 = gbeg + tid; s2 < gend; s2 += 1024) {
            uint64_t key = grp[s2];
            unsigned int k  = ~((unsigned int)(key >> 32));
            unsigned int sb = (k >> 8) & 0xfffu;
            unsigned int d  = sufx2[sb] + atomicAdd(&hist2[sb], 1u);
            grp2[d] = key;   // d < m <= CAND_MAX
        }
        __syncthreads();

        for (unsigned int s2 = tid; s2 < m; s2 += 1024) {
            uint64_t key = grp2[s2];
            unsigned int k   = ~((unsigned int)(key >> 32));
            unsigned int sb  = (k >> 8) & 0xfffu;
            unsigned int b2  = sufx2[sb];
            unsigned int e2  = b2 + hist2[sb];
            unsigned int rank = gbeg + b2;
            for (unsigned int g = b2; g < e2; ++g)
                rank += (grp2[g] < key) ? 1u : 0u;
            if (rank < PRE_N)
                decode_store(key, rank, n, breg, wsBoxes, wsScores, wsValid);
        }
        __syncthreads();   // protect hist2/sufx2/grp2 reuse next iteration
    }

    // ---- small bins: rank via 8-wide unrolled scan + decode ----------------
    for (unsigned int slot = tid; slot < total; slot += 1024) {
        const uint64_t key = grp[slot];
        const unsigned int hi = (unsigned int)(key >> 32);   // = ~k
        const unsigned int b  = 4095u - (hi >> 20);          // bin of k
        const unsigned int cntb = hist[b];
        if (cntb > (unsigned int)BIG_BIN) continue;          // handled above
        const unsigned int gbeg = sufx[b];
        const unsigned int gend = min(gbeg + cntb, (unsigned int)CAND_MAX);
        unsigned int rank = gbeg;
        unsigned int g = gbeg;
        for (; g + 8u <= gend; g += 8u) {
            uint64_t v0 = grp[g+0], v1 = grp[g+1], v2 = grp[g+2], v3 = grp[g+3];
            uint64_t v4 = grp[g+4], v5 = grp[g+5], v6 = grp[g+6], v7 = grp[g+7];
            unsigned int r0 = (v0 < key) ? 1u : 0u;
            r0 += (v1 < key) ? 1u : 0u;
            r0 += (v2 < key) ? 1u : 0u;
            r0 += (v3 < key) ? 1u : 0u;
            r0 += (v4 < key) ? 1u : 0u;
            r0 += (v5 < key) ? 1u : 0u;
            r0 += (v6 < key) ? 1u : 0u;
            r0 += (v7 < key) ? 1u : 0u;
            rank += r0;
        }
        for (; g < gend; ++g)
            rank += (grp[g] < key) ? 1u : 0u;
        if (rank >= PRE_N) continue;
        decode_store(key, rank, n, breg, wsBoxes, wsScores, wsValid);
    }
}

// ---------------------------------------------------------------------------
// Kernel C (verified R11, unchanged): div-free IoU predicate, ballot mask
// word, LDS-staged contiguous store. One block (8 waves) per row-tile.
// ---------------------------------------------------------------------------
__global__ __launch_bounds__(512) void nms_mask(
    const float* __restrict__ wsBoxes, uint64_t* __restrict__ mask)
{
    const int blk  = blockIdx.x;
    const int n    = blk >> 5;
    const int i_t  = blk & 31;
    const int tid  = threadIdx.x;
    const int lane = tid & 63;
    const int wv   = tid >> 6;   // 0..7

    __shared__ uint64_t tile[64 * 33];   // padded pitch 33

    for (int idx = tid; idx < 64 * 33; idx += 512) tile[idx] = 0ull;
    __syncthreads();

    const int r = i_t * 64 + lane;
    float4 rb = (r < PRE_N) ? ((const float4*)wsBoxes)[n * PRE_N + r]
                            : make_float4(0.f, 0.f, 0.f, 0.f);
    float ra = (rb.z - rb.x + 1.0f) * (rb.w - rb.y + 1.0f);

    for (int j_t = i_t + wv; j_t < 32; j_t += 8) {
        const int j = j_t * 64 + lane;
        float4 cb = (j < PRE_N) ? ((const float4*)wsBoxes)[n * PRE_N + j]
                                : make_float4(3e30f, 3e30f, 3e30f, 3e30f);
        float ca = (cb.z - cb.x + 1.0f) * (cb.w - cb.y + 1.0f);
        const uint64_t jmask = (j_t == 31) ? 0xFFFFull : ~0ull;
        const bool diag = (j_t == i_t);
        uint64_t myword = 0ull;

        #pragma unroll
        for (int c = 0; c < 64; ++c) {
            float rx1 = __int_as_float(__builtin_amdgcn_readlane(__float_as_int(rb.x), c));
            float ry1 = __int_as_float(__builtin_amdgcn_readlane(__float_as_int(rb.y), c));
            float rx2 = __int_as_float(__builtin_amdgcn_readlane(__float_as_int(rb.z), c));
            float ry2 = __int_as_float(__builtin_amdgcn_readlane(__float_as_int(rb.w), c));
            float rar = __int_as_float(__builtin_amdgcn_readlane(__float_as_int(ra), c));
            float xx1 = fmaxf(rx1, cb.x), yy1 = fmaxf(ry1, cb.y);
            float xx2 = fminf(rx2, cb.z), yy2 = fminf(ry2, cb.w);
            float ww = fmaxf(xx2 - xx1 + 1.0f, 0.0f);
            float hh = fmaxf(yy2 - yy1 + 1.0f, 0.0f);
            float inter = ww * hh;
            float denom = rar + ca - inter;
            unsigned long long bits = __ballot(inter > NMS_TH * denom) & jmask;
            if (diag) bits &= (c == 63) ? 0ull : ((~0ull) << (c + 1));
            if (lane == c) myword = bits;
        }
        tile[lane * 33 + j_t] = myword;
    }
    __syncthreads();

    uint64_t* mrow = mask + ((size_t)n * PRE_N + (size_t)i_t * 64) * 32;
    const int cmax = (i_t == 31) ? 16 : 64;
    for (int idx = tid; idx < cmax * 32; idx += 512) {
        const int rr = idx >> 5, w = idx & 31;
        mrow[idx] = tile[rr * 33 + w];
    }
}

// ---------------------------------------------------------------------------
// Kernel D (verified R8, unchanged): serial greedy scan, inline asm, 64-slot
// VGPR ring, pure-SALU chain, early-exit at kept=1000.
// ---------------------------------------------------------------------------
#define SL(n,b) \
    "global_load_dword v" #n ", %[voff], %[sbase]\n\t" \
    "v_add_u32 %[voff], 0x100, %[voff]\n\t"

#define SS(n,b) \
    "s_waitcnt vmcnt(63)\n\t" \
    "v_readlane_b32 %[t], v" #n ", %[lw]\n\t" \
    "s_bitcmp1_b32 %[win], " #b "\n\t" \
    "s_cselect_b32 %[m], 0, -1\n\t" \
    "s_sub_i32 %[kept], %[kept], %[m]\n\t" \
    "s_and_b32 %[t], %[t], %[m]\n\t" \
    "s_or_b32 %[win], %[win], %[t]\n\t" \
    "v_and_b32 v" #n ", %[m], v" #n "\n\t" \
    "v_or_b32 %[rem], %[rem], v" #n "\n\t" \
    "global_load_dword v" #n ", %[voff], %[sbase]\n\t" \
    "v_add_u32 %[voff], 0x100, %[voff]\n\t"

#define SN(n,b,w) \
    "s_waitcnt vmcnt(" #w ")\n\t" \
    "v_readlane_b32 %[t], v" #n ", %[lw]\n\t" \
    "s_bitcmp1_b32 %[win], " #b "\n\t" \
    "s_cselect_b32 %[m], 0, -1\n\t" \
    "s_sub_i32 %[kept], %[kept], %[m]\n\t" \
    "s_and_b32 %[t], %[t], %[m]\n\t" \
    "s_or_b32 %[win], %[win], %[t]\n\t" \
    "v_and_b32 v" #n ", %[m], v" #n "\n\t" \
    "v_or_b32 %[rem], %[rem], v" #n "\n\t"

#define SWIN \
    "s_add_u32 %[lw], %[lw], 1\n\t" \
    "v_readlane_b32 %[t], %[rem], %[lw]\n\t" \
    "s_mov_b32 %[win], %[t]\n\t"

#define ROW_A(M) M(64,0) M(65,1) M(66,2) M(67,3) M(68,4) M(69,5) M(70,6) M(71,7) \
    M(72,8) M(73,9) M(74,10) M(75,11) M(76,12) M(77,13) M(78,14) M(79,15) \
    M(80,16) M(81,17) M(82,18) M(83,19) M(84,20) M(85,21) M(86,22) M(87,23) \
    M(88,24) M(89,25) M(90,26) M(91,27) M(92,28) M(93,29) M(94,30) M(95,31)
#define ROW_B(M) M(96,0) M(97,1) M(98,2) M(99,3) M(100,4) M(101,5) M(102,6) M(103,7) \
    M(104,8) M(105,9) M(106,10) M(107,11) M(108,12) M(109,13) M(110,14) M(111,15) \
    M(112,16) M(113,17) M(114,18) M(115,19) M(116,20) M(117,21) M(118,22) M(119,23) \
    M(120,24) M(121,25) M(122,26) M(123,27) M(124,28) M(125,29) M(126,30) M(127,31)

__global__ __launch_bounds__(256) void nms_scan_select(
    const float* __restrict__ wsBoxes, const float* __restrict__ wsScores,
    const int* __restrict__ wsValid, const uint64_t* __restrict__ mask,
    float* __restrict__ out)
{
    const int n   = blockIdx.x;
    const int tid = threadIdx.x;

    __shared__ __align__(8) unsigned char invb[256];
    __shared__ unsigned int keepw32[64];
    __shared__ int sscan[256];

    unsigned int byte = 0xFFu;
    if (tid < PRE_N / 8) {
        byte = 0u;
        for (int q = 0; q < 8; ++q)
            byte |= (wsValid[n * PRE_N + tid * 8 + q] ? 0u : 1u) << q;
    }
    invb[tid] = (unsigned char)byte;
    __syncthreads();

    if (tid < 64) {
        unsigned int rem = ((const unsigned int*)invb)[tid];
        unsigned long long sbase =
            (unsigned long long)(const void*)(mask + (size_t)n * PRE_N * 32);
        unsigned int voff = (unsigned int)(tid * 4);
        int win_, m_, t_, lw_, kept_, cnt_;

        asm volatile(
            "s_waitcnt vmcnt(0) lgkmcnt(0)\n\t"
            "s_mov_b32 %[kept], 0\n\t"
            "s_mov_b32 %[lw], 0\n\t"
            ROW_A(SL) ROW_B(SL)
            "v_readlane_b32 %[t], %[rem], %[lw]\n\t"
            "s_mov_b32 %[win], %[t]\n\t"
            "s_mov_b32 %[cnt], 30\n\t"
            "Lnms_%=:\n\t"
            ROW_A(SS)
            SWIN
            ROW_B(SS)
            SWIN
            "s_cmp_ge_i32 %[kept], 0x3e8\n\t"
            "s_cbranch_scc1 Lend_%=\n\t"
            "s_sub_u32 %[cnt], %[cnt], 1\n\t"
            "s_cmp_lg_u32 %[cnt], 0\n\t"
            "s_cbranch_scc1 Lnms_%=\n\t"
            SS(64,0) SS(65,1) SS(66,2) SS(67,3) SS(68,4) SS(69,5) SS(70,6) SS(71,7)
            SS(72,8) SS(73,9) SS(74,10) SS(75,11) SS(76,12) SS(77,13) SS(78,14) SS(79,15)
            SN(80,16,63) SN(81,17,62) SN(82,18,61) SN(83,19,60)
            SN(84,20,59) SN(85,21,58) SN(86,22,57) SN(87,23,56)
            SN(88,24,55) SN(89,25,54) SN(90,26,53) SN(91,27,52)
            SN(92,28,51) SN(93,29,50) SN(94,30,49) SN(95,31,48)
            SWIN
            SN(96,0,47) SN(97,1,46) SN(98,2,45) SN(99,3,44)
            SN(100,4,43) SN(101,5,42) SN(102,6,41) SN(103,7,40)
            SN(104,8,39) SN(105,9,38) SN(106,10,37) SN(107,11,36)
            SN(108,12,35) SN(109,13,34) SN(110,14,33) SN(111,15,32)
            SN(112,16,31) SN(113,17,30) SN(114,18,29) SN(115,19,28)
            SN(116,20,27) SN(117,21,26) SN(118,22,25) SN(119,23,24)
            SN(120,24,23) SN(121,25,22) SN(122,26,21) SN(123,27,20)
            SN(124,28,19) SN(125,29,18) SN(126,30,17) SN(127,31,16)
            SWIN
            SN(64,0,15) SN(65,1,14) SN(66,2,13) SN(67,3,12)
            SN(68,4,11) SN(69,5,10) SN(70,6,9) SN(71,7,8)
            SN(72,8,7) SN(73,9,6) SN(74,10,5) SN(75,11,4)
            SN(76,12,3) SN(77,13,2) SN(78,14,1) SN(79,15,0)
            "Lend_%=:\n\t"
            "s_waitcnt vmcnt(0)\n\t"
            : [rem]"+v"(rem), [voff]"+v"(voff),
              [win]"=&s"(win_), [m]"=&s"(m_), [t]"=&s"(t_),
              [lw]"=&s"(lw_), [kept]"=&s"(kept_), [cnt]"=&s"(cnt_)
            : [sbase]"s"(sbase)
            : "scc", "vcc", "memory",
              "v64","v65","v66","v67","v68","v69","v70","v71",
              "v72","v73","v74","v75","v76","v77","v78","v79",
              "v80","v81","v82","v83","v84","v85","v86","v87",
              "v88","v89","v90","v91","v92","v93","v94","v95",
              "v96","v97","v98","v99","v100","v101","v102","v103",
              "v104","v105","v106","v107","v108","v109","v110","v111",
              "v112","v113","v114","v115","v116","v117","v118","v119",
              "v120","v121","v122","v123","v124","v125","v126","v127");

        keepw32[tid] = ~rem;
    }
    __syncthreads();

    int c[8]; const int base8 = tid * 8;
    int lsum = 0;
    for (int q = 0; q < 8; ++q) {
        const int i = base8 + q;
        c[q] = (i < PRE_N) ? (int)((keepw32[i >> 5] >> (i & 31)) & 1u) : 0;
        lsum += c[q];
    }
    sscan[tid] = lsum;
    __syncthreads();
    for (int off = 1; off < 256; off <<= 1) {
        int v = (tid >= off) ? sscan[tid - off] : 0;
        __syncthreads();
        sscan[tid] += v;
        __syncthreads();
    }
    const int excl  = sscan[tid] - lsum;
    const int total = sscan[255];

    float* ob  = out + n * POST_N * 4;
    float* osc = out + NIMG * POST_N * 4 + n * POST_N;
    float* ovd = out + NIMG * POST_N * 5 + n * POST_N;

    for (int i = tid; i < POST_N * 4; i += 256) ob[i] = 0.0f;
    for (int i = tid; i < POST_N; i += 256) osc[i] = 0.0f;
    const int lim = min(total, POST_N);
    for (int i = tid; i < POST_N; i += 256) ovd[i] = (i < lim) ? 1.0f : 0.0f;
    __syncthreads();

    int run = excl;
    for (int q = 0; q < 8; ++q) {
        const int i = base8 + q;
        if (i < PRE_N && c[q]) {
            if (run < POST_N) {
                float4 b = ((const float4*)wsBoxes)[n * PRE_N + i];
                ob[run * 4 + 0] = b.x;
                ob[run * 4 + 1] = b.y;
                ob[run * 4 + 2] = b.z;
                ob[run * 4 + 3] = b.w;
                osc[run] = wsScores[n * PRE_N + i];
            }
            run++;
        }
    }
}

extern "C" void kernel_launch(void* const* d_in, const int* in_sizes, int n_in,
                              void* d_out, int out_size, void* d_ws, size_t ws_size,
                              hipStream_t stream) {
    const float* obj  = (const float*)d_in[0];
    const float* breg = (const float*)d_in[1];
    // d_in[2] anchors unused (computed inline, exact in f32)
    float* ws        = (float*)d_ws;
    float* wsBoxes   = ws;                      // 64000 floats
    float* wsScores  = ws + 64000;              // 16000 floats
    int*   wsValid   = (int*)(ws + 80000);      // 16000 ints
    uint64_t* wsMask = (uint64_t*)(ws + 96000); // 8*2000*32 u64 = 4.096 MB

    topk_decode<<<NIMG, 1024, 0, stream>>>(obj, breg, wsBoxes, wsScores, wsValid);
    nms_mask<<<NIMG * 32, 512, 0, stream>>>(wsBoxes, wsMask);
    nms_scan_select<<<NIMG, 256, 0, stream>>>(wsBoxes, wsScores, wsValid, wsMask,
                                              (float*)d_out);
}

// Round 4
// 167.580 us; speedup vs baseline: 1.0650x; 1.0650x over previous
//
#include <hip/hip_runtime.h>
#include <math.h>
#include <stdint.h>

#define NIMG   8
#define NA     30000      // H*W*A = 100*100*3
#define NQ4    7500       // NA/4 float4s
#define PRE_N  2000
#define POST_N 1000
#define NMS_TH 0.7f
#define DCLIP  4.135166556742356f   // log(1000/16)
#define IMGF   1600.0f
#define IMGM1  1599.0f
#define CAND_MAX 4096
#define HPITCH 4104       // 4096 + 8: replica bank-spread padding

// ws layout (floats): boxes [8][2000][4] @0, scores [8][2000] @64000,
//   valid(int) [8][2000] @80000, mask(u64) [8][2000][32] @96000.

// ---------------------------------------------------------------------------
// decode + store helper (verified math, unchanged)
// ---------------------------------------------------------------------------
__device__ __forceinline__ void decode_store(
    uint64_t key, unsigned int rank, int n, const float* __restrict__ breg,
    float* __restrict__ wsBoxes, float* __restrict__ wsScores,
    int* __restrict__ wsValid)
{
    unsigned int idx = (unsigned int)key;
    unsigned int k   = ~((unsigned int)(key >> 32));
    unsigned int u   = (k & 0x80000000u) ? (k & 0x7fffffffu) : ~k;
    float logit = __uint_as_float(u);
    float score = 1.0f / (1.0f + expf(-logit));

    int a = idx % 3, t = idx / 3, w = t % 100, h = t / 100;
    const float* bp = breg + n*120000 + (a*4)*10000 + t;
    float dx = bp[0], dy = bp[10000], dw = bp[20000], dh = bp[30000];

    float half = (a == 0) ? 32.0f : ((a == 1) ? 64.0f : 128.0f);
    float cx = w * 16.0f + 8.0f, cy = h * 16.0f + 8.0f;
    float x1 = cx - half, y1 = cy - half, x2 = cx + half, y2 = cy + half;
    float wd = x2 - x1 + 1.0f, hg = y2 - y1 + 1.0f;
    float cxr = x1 + 0.5f * wd, cyr = y1 + 0.5f * hg;
    dw = fminf(dw, DCLIP); dh = fminf(dh, DCLIP);
    float pcx = dx * wd + cxr, pcy = dy * hg + cyr;
    float pw = expf(dw) * wd, ph = expf(dh) * hg;
    float px1 = pcx - 0.5f * pw, py1 = pcy - 0.5f * ph;
    float px2 = pcx + 0.5f * pw - 1.0f, py2 = pcy + 0.5f * ph - 1.0f;
    px1 = fminf(fmaxf(px1, 0.0f), IMGM1);
    px2 = fminf(fmaxf(px2, 0.0f), IMGM1);
    py1 = fminf(fmaxf(py1, 0.0f), IMGM1);
    py2 = fminf(fmaxf(py2, 0.0f), IMGM1);
    float wss = px2 - px1 + 1.0f, hss = py2 - py1 + 1.0f;
    float xc = px1 + wss * 0.5f, yc = py1 + hss * 0.5f;
    int valid = (wss >= 0.0f) && (hss >= 0.0f) && (xc < IMGF) && (yc < IMGF);

    ((float4*)wsBoxes)[n * PRE_N + (int)rank] = make_float4(px1, py1, px2, py2);
    wsScores[n * PRE_N + (int)rank] = score;
    wsValid [n * PRE_N + (int)rank] = valid;
}

__device__ __forceinline__ unsigned int keyof(float f) {
    unsigned int u = __float_as_uint(f);
    return (u & 0x80000000u) ? ~u : (u | 0x80000000u);
}

// ---------------------------------------------------------------------------
// Kernel AB: fused hist + suffix-sum + bin-grouped rank + decode.
// R4: (1) register-resident obj (8 float4/thread loaded once, feeds BOTH
// passes — kills the rolled-loop load-latency chains that made VALUBusy 0.6%);
// (2) 4-replica bank-padded histogram with bump-allocator bases (same-address
// LDS atomic serialization / 4); (3) R3's per-bin radix reverted (it was
// measured +6us overhead vs the 8-wide scan it replaced).
// ---------------------------------------------------------------------------
__global__ __launch_bounds__(1024) void topk_decode(
    const float* __restrict__ obj, const float* __restrict__ breg,
    float* __restrict__ wsBoxes, float* __restrict__ wsScores,
    int* __restrict__ wsValid)
{
    const int n    = blockIdx.x;
    const int tid  = threadIdx.x;
    const int lane = tid & 63;
    const int wid  = tid >> 6;
    const int rep  = wid & 3;

    __shared__ unsigned int   histf[4 * HPITCH]; // counts -> bump bases (~64KB)
    __shared__ unsigned short sufx[4096];        // bin start slots
    __shared__ uint64_t       grp[CAND_MAX];     // bin-grouped keys (32KB)
    __shared__ unsigned int   wsum[16];
    __shared__ unsigned int   sbstar;

    for (int b = tid; b < 4 * HPITCH; b += 1024) histf[b] = 0u;
    __syncthreads();

    // ---- load this thread's 8 float4s once (8 outstanding loads) -----------
    const float4* obj4 = (const float4*)(obj + n * NA);   // 7500 float4, 16B-aligned
    float4 v[8];
    #pragma unroll
    for (int kk = 0; kk < 7; ++kk) v[kk] = obj4[tid + kk * 1024];
    v[7] = make_float4(0.f, 0.f, 0.f, 0.f);
    if (tid < NQ4 - 7 * 1024) v[7] = obj4[tid + 7 * 1024];   // 332 tail threads

    // ---- pass 1: replica histogram from registers --------------------------
    #pragma unroll
    for (int kk = 0; kk < 8; ++kk) {
        if (kk == 7 && tid >= NQ4 - 7 * 1024) continue;
        atomicAdd(&histf[rep * HPITCH + (keyof(v[kk].x) >> 20)], 1u);
        atomicAdd(&histf[rep * HPITCH + (keyof(v[kk].y) >> 20)], 1u);
        atomicAdd(&histf[rep * HPITCH + (keyof(v[kk].z) >> 20)], 1u);
        atomicAdd(&histf[rep * HPITCH + (keyof(v[kk].w) >> 20)], 1u);
    }
    __syncthreads();

    // ---- suffix-scan of totals (verified structure), bump-base conversion --
    unsigned int c0, c1, c2, c3;
    {
        const int b0 = tid * 4;
        c0 = histf[b0+0] + histf[HPITCH+b0+0] + histf[2*HPITCH+b0+0] + histf[3*HPITCH+b0+0];
        c1 = histf[b0+1] + histf[HPITCH+b0+1] + histf[2*HPITCH+b0+1] + histf[3*HPITCH+b0+1];
        c2 = histf[b0+2] + histf[HPITCH+b0+2] + histf[2*HPITCH+b0+2] + histf[3*HPITCH+b0+2];
        c3 = histf[b0+3] + histf[HPITCH+b0+3] + histf[2*HPITCH+b0+3] + histf[3*HPITCH+b0+3];
    }
    unsigned int p = c0 + c1 + c2 + c3;
    unsigned int s = p;
    #pragma unroll
    for (int off = 1; off < 64; off <<= 1) {
        unsigned int vv = __shfl_down(s, off);
        if (lane + off < 64) s += vv;
    }
    if (lane == 0) wsum[wid] = s;
    __syncthreads();
    unsigned int wafter = 0;
    for (int w = wid + 1; w < 16; ++w) wafter += wsum[w];
    unsigned int after = (s - p) + wafter;   // elems in bins > 4t+3
    {
        unsigned int S3 = after + c3;        // elems in bins > 4t+2
        unsigned int S2 = S3 + c2;           // elems in bins > 4t+1
        unsigned int S1 = S2 + c1;           // elems in bins > 4t+0
        unsigned int S0 = S1 + c0;
        if (S3 >= PRE_N && after < PRE_N) { sbstar = tid*4+3; }
        if (S2 >= PRE_N && S3    < PRE_N) { sbstar = tid*4+2; }
        if (S1 >= PRE_N && S2    < PRE_N) { sbstar = tid*4+1; }
        if (S0 >= PRE_N && S1    < PRE_N) { sbstar = tid*4+0; }
        sufx[tid*4+0] = (unsigned short)S1;
        sufx[tid*4+1] = (unsigned short)S2;
        sufx[tid*4+2] = (unsigned short)S3;
        sufx[tid*4+3] = (unsigned short)after;

        // counts -> per-replica bump bases (each thread touches only own bins)
        const unsigned int st[4] = {S1, S2, S3, after};
        #pragma unroll
        for (int q = 0; q < 4; ++q) {
            const int b = tid*4 + q;
            unsigned int base = st[q];
            #pragma unroll
            for (int r = 0; r < 4; ++r) {
                unsigned int c = histf[r * HPITCH + b];
                histf[r * HPITCH + b] = base;
                base += c;
            }
        }
    }
    __syncthreads();
    const unsigned int bstar = sbstar;

    // ---- pass 2: bin-grouped placement from registers ----------------------
    #pragma unroll
    for (int kk = 0; kk < 8; ++kk) {
        if (kk == 7 && tid >= NQ4 - 7 * 1024) continue;
        const float fv[4] = {v[kk].x, v[kk].y, v[kk].z, v[kk].w};
        #pragma unroll
        for (int e = 0; e < 4; ++e) {
            unsigned int k = keyof(fv[e]);
            unsigned int b = k >> 20;
            if (b < bstar) continue;
            int j = (tid + kk * 1024) * 4 + e;
            int a = j / 10000, t = j - a * 10000;
            uint64_t key = (((uint64_t)(~k)) << 32) | (unsigned int)(t * 3 + a);
            unsigned int slot = atomicAdd(&histf[rep * HPITCH + b], 1u);
            if (slot < CAND_MAX) grp[slot] = key;
        }
    }
    __syncthreads();

    // after pass2, histf[3][b] = end of bin b's slot region
    const unsigned int total = min(histf[3 * HPITCH + bstar], (unsigned int)CAND_MAX);

    // ---- rank via 8-wide unrolled scan + decode ----------------------------
    for (unsigned int slot = tid; slot < total; slot += 1024) {
        const uint64_t key = grp[slot];
        const unsigned int hi = (unsigned int)(key >> 32);   // = ~k
        const unsigned int b  = 4095u - (hi >> 20);          // bin of k
        const unsigned int gbeg = sufx[b];
        const unsigned int gend = min(histf[3 * HPITCH + b], (unsigned int)CAND_MAX);
        unsigned int rank = gbeg;
        unsigned int g = gbeg;
        for (; g + 8u <= gend; g += 8u) {
            uint64_t v0 = grp[g+0], v1 = grp[g+1], v2 = grp[g+2], v3 = grp[g+3];
            uint64_t v4 = grp[g+4], v5 = grp[g+5], v6 = grp[g+6], v7 = grp[g+7];
            unsigned int r0 = (v0 < key) ? 1u : 0u;
            r0 += (v1 < key) ? 1u : 0u;
            r0 += (v2 < key) ? 1u : 0u;
            r0 += (v3 < key) ? 1u : 0u;
            r0 += (v4 < key) ? 1u : 0u;
            r0 += (v5 < key) ? 1u : 0u;
            r0 += (v6 < key) ? 1u : 0u;
            r0 += (v7 < key) ? 1u : 0u;
            rank += r0;
        }
        for (; g < gend; ++g)
            rank += (grp[g] < key) ? 1u : 0u;
        if (rank >= PRE_N) continue;
        decode_store(key, rank, n, breg, wsBoxes, wsScores, wsValid);
    }
}

// ---------------------------------------------------------------------------
// Kernel C (verified R11, unchanged): div-free IoU predicate, ballot mask
// word, LDS-staged contiguous store. One block (8 waves) per row-tile.
// ---------------------------------------------------------------------------
__global__ __launch_bounds__(512) void nms_mask(
    const float* __restrict__ wsBoxes, uint64_t* __restrict__ mask)
{
    const int blk  = blockIdx.x;
    const int n    = blk >> 5;
    const int i_t  = blk & 31;
    const int tid  = threadIdx.x;
    const int lane = tid & 63;
    const int wv   = tid >> 6;   // 0..7

    __shared__ uint64_t tile[64 * 33];   // padded pitch 33

    for (int idx = tid; idx < 64 * 33; idx += 512) tile[idx] = 0ull;
    __syncthreads();

    const int r = i_t * 64 + lane;
    float4 rb = (r < PRE_N) ? ((const float4*)wsBoxes)[n * PRE_N + r]
                            : make_float4(0.f, 0.f, 0.f, 0.f);
    float ra = (rb.z - rb.x + 1.0f) * (rb.w - rb.y + 1.0f);

    for (int j_t = i_t + wv; j_t < 32; j_t += 8) {
        const int j = j_t * 64 + lane;
        float4 cb = (j < PRE_N) ? ((const float4*)wsBoxes)[n * PRE_N + j]
                                : make_float4(3e30f, 3e30f, 3e30f, 3e30f);
        float ca = (cb.z - cb.x + 1.0f) * (cb.w - cb.y + 1.0f);
        const uint64_t jmask = (j_t == 31) ? 0xFFFFull : ~0ull;
        const bool diag = (j_t == i_t);
        uint64_t myword = 0ull;

        #pragma unroll
        for (int c = 0; c < 64; ++c) {
            float rx1 = __int_as_float(__builtin_amdgcn_readlane(__float_as_int(rb.x), c));
            float ry1 = __int_as_float(__builtin_amdgcn_readlane(__float_as_int(rb.y), c));
            float rx2 = __int_as_float(__builtin_amdgcn_readlane(__float_as_int(rb.z), c));
            float ry2 = __int_as_float(__builtin_amdgcn_readlane(__float_as_int(rb.w), c));
            float rar = __int_as_float(__builtin_amdgcn_readlane(__float_as_int(ra), c));
            float xx1 = fmaxf(rx1, cb.x), yy1 = fmaxf(ry1, cb.y);
            float xx2 = fminf(rx2, cb.z), yy2 = fminf(ry2, cb.w);
            float ww = fmaxf(xx2 - xx1 + 1.0f, 0.0f);
            float hh = fmaxf(yy2 - yy1 + 1.0f, 0.0f);
            float inter = ww * hh;
            float denom = rar + ca - inter;
            unsigned long long bits = __ballot(inter > NMS_TH * denom) & jmask;
            if (diag) bits &= (c == 63) ? 0ull : ((~0ull) << (c + 1));
            if (lane == c) myword = bits;
        }
        tile[lane * 33 + j_t] = myword;
    }
    __syncthreads();

    uint64_t* mrow = mask + ((size_t)n * PRE_N + (size_t)i_t * 64) * 32;
    const int cmax = (i_t == 31) ? 16 : 64;
    for (int idx = tid; idx < cmax * 32; idx += 512) {
        const int rr = idx >> 5, w = idx & 31;
        mrow[idx] = tile[rr * 33 + w];
    }
}

// ---------------------------------------------------------------------------
// Kernel D (verified R8, unchanged): serial greedy scan, inline asm, 64-slot
// VGPR ring, pure-SALU chain, early-exit at kept=1000.
// ---------------------------------------------------------------------------
#define SL(n,b) \
    "global_load_dword v" #n ", %[voff], %[sbase]\n\t" \
    "v_add_u32 %[voff], 0x100, %[voff]\n\t"

#define SS(n,b) \
    "s_waitcnt vmcnt(63)\n\t" \
    "v_readlane_b32 %[t], v" #n ", %[lw]\n\t" \
    "s_bitcmp1_b32 %[win], " #b "\n\t" \
    "s_cselect_b32 %[m], 0, -1\n\t" \
    "s_sub_i32 %[kept], %[kept], %[m]\n\t" \
    "s_and_b32 %[t], %[t], %[m]\n\t" \
    "s_or_b32 %[win], %[win], %[t]\n\t" \
    "v_and_b32 v" #n ", %[m], v" #n "\n\t" \
    "v_or_b32 %[rem], %[rem], v" #n "\n\t" \
    "global_load_dword v" #n ", %[voff], %[sbase]\n\t" \
    "v_add_u32 %[voff], 0x100, %[voff]\n\t"

#define SN(n,b,w) \
    "s_waitcnt vmcnt(" #w ")\n\t" \
    "v_readlane_b32 %[t], v" #n ", %[lw]\n\t" \
    "s_bitcmp1_b32 %[win], " #b "\n\t" \
    "s_cselect_b32 %[m], 0, -1\n\t" \
    "s_sub_i32 %[kept], %[kept], %[m]\n\t" \
    "s_and_b32 %[t], %[t], %[m]\n\t" \
    "s_or_b32 %[win], %[win], %[t]\n\t" \
    "v_and_b32 v" #n ", %[m], v" #n "\n\t" \
    "v_or_b32 %[rem], %[rem], v" #n "\n\t"

#define SWIN \
    "s_add_u32 %[lw], %[lw], 1\n\t" \
    "v_readlane_b32 %[t], %[rem], %[lw]\n\t" \
    "s_mov_b32 %[win], %[t]\n\t"

#define ROW_A(M) M(64,0) M(65,1) M(66,2) M(67,3) M(68,4) M(69,5) M(70,6) M(71,7) \
    M(72,8) M(73,9) M(74,10) M(75,11) M(76,12) M(77,13) M(78,14) M(79,15) \
    M(80,16) M(81,17) M(82,18) M(83,19) M(84,20) M(85,21) M(86,22) M(87,23) \
    M(88,24) M(89,25) M(90,26) M(91,27) M(92,28) M(93,29) M(94,30) M(95,31)
#define ROW_B(M) M(96,0) M(97,1) M(98,2) M(99,3) M(100,4) M(101,5) M(102,6) M(103,7) \
    M(104,8) M(105,9) M(106,10) M(107,11) M(108,12) M(109,13) M(110,14) M(111,15) \
    M(112,16) M(113,17) M(114,18) M(115,19) M(116,20) M(117,21) M(118,22) M(119,23) \
    M(120,24) M(121,25) M(122,26) M(123,27) M(124,28) M(125,29) M(126,30) M(127,31)

__global__ __launch_bounds__(256) void nms_scan_select(
    const float* __restrict__ wsBoxes, const float* __restrict__ wsScores,
    const int* __restrict__ wsValid, const uint64_t* __restrict__ mask,
    float* __restrict__ out)
{
    const int n   = blockIdx.x;
    const int tid = threadIdx.x;

    __shared__ __align__(8) unsigned char invb[256];
    __shared__ unsigned int keepw32[64];
    __shared__ int sscan[256];

    unsigned int byte = 0xFFu;
    if (tid < PRE_N / 8) {
        byte = 0u;
        for (int q = 0; q < 8; ++q)
            byte |= (wsValid[n * PRE_N + tid * 8 + q] ? 0u : 1u) << q;
    }
    invb[tid] = (unsigned char)byte;
    __syncthreads();

    if (tid < 64) {
        unsigned int rem = ((const unsigned int*)invb)[tid];
        unsigned long long sbase =
            (unsigned long long)(const void*)(mask + (size_t)n * PRE_N * 32);
        unsigned int voff = (unsigned int)(tid * 4);
        int win_, m_, t_, lw_, kept_, cnt_;

        asm volatile(
            "s_waitcnt vmcnt(0) lgkmcnt(0)\n\t"
            "s_mov_b32 %[kept], 0\n\t"
            "s_mov_b32 %[lw], 0\n\t"
            ROW_A(SL) ROW_B(SL)
            "v_readlane_b32 %[t], %[rem], %[lw]\n\t"
            "s_mov_b32 %[win], %[t]\n\t"
            "s_mov_b32 %[cnt], 30\n\t"
            "Lnms_%=:\n\t"
            ROW_A(SS)
            SWIN
            ROW_B(SS)
            SWIN
            "s_cmp_ge_i32 %[kept], 0x3e8\n\t"
            "s_cbranch_scc1 Lend_%=\n\t"
            "s_sub_u32 %[cnt], %[cnt], 1\n\t"
            "s_cmp_lg_u32 %[cnt], 0\n\t"
            "s_cbranch_scc1 Lnms_%=\n\t"
            SS(64,0) SS(65,1) SS(66,2) SS(67,3) SS(68,4) SS(69,5) SS(70,6) SS(71,7)
            SS(72,8) SS(73,9) SS(74,10) SS(75,11) SS(76,12) SS(77,13) SS(78,14) SS(79,15)
            SN(80,16,63) SN(81,17,62) SN(82,18,61) SN(83,19,60)
            SN(84,20,59) SN(85,21,58) SN(86,22,57) SN(87,23,56)
            SN(88,24,55) SN(89,25,54) SN(90,26,53) SN(91,27,52)
            SN(92,28,51) SN(93,29,50) SN(94,30,49) SN(95,31,48)
            SWIN
            SN(96,0,47) SN(97,1,46) SN(98,2,45) SN(99,3,44)
            SN(100,4,43) SN(101,5,42) SN(102,6,41) SN(103,7,40)
            SN(104,8,39) SN(105,9,38) SN(106,10,37) SN(107,11,36)
            SN(108,12,35) SN(109,13,34) SN(110,14,33) SN(111,15,32)
            SN(112,16,31) SN(113,17,30) SN(114,18,29) SN(115,19,28)
            SN(116,20,27) SN(117,21,26) SN(118,22,25) SN(119,23,24)
            SN(120,24,23) SN(121,25,22) SN(122,26,21) SN(123,27,20)
            SN(124,28,19) SN(125,29,18) SN(126,30,17) SN(127,31,16)
            SWIN
            SN(64,0,15) SN(65,1,14) SN(66,2,13) SN(67,3,12)
            SN(68,4,11) SN(69,5,10) SN(70,6,9) SN(71,7,8)
            SN(72,8,7) SN(73,9,6) SN(74,10,5) SN(75,11,4)
            SN(76,12,3) SN(77,13,2) SN(78,14,1) SN(79,15,0)
            "Lend_%=:\n\t"
            "s_waitcnt vmcnt(0)\n\t"
            : [rem]"+v"(rem), [voff]"+v"(voff),
              [win]"=&s"(win_), [m]"=&s"(m_), [t]"=&s"(t_),
              [lw]"=&s"(lw_), [kept]"=&s"(kept_), [cnt]"=&s"(cnt_)
            : [sbase]"s"(sbase)
            : "scc", "vcc", "memory",
              "v64","v65","v66","v67","v68","v69","v70","v71",
              "v72","v73","v74","v75","v76","v77","v78","v79",
              "v80","v81","v82","v83","v84","v85","v86","v87",
              "v88","v89","v90","v91","v92","v93","v94","v95",
              "v96","v97","v98","v99","v100","v101","v102","v103",
              "v104","v105","v106","v107","v108","v109","v110","v111",
              "v112","v113","v114","v115","v116","v117","v118","v119",
              "v120","v121","v122","v123","v124","v125","v126","v127");

        keepw32[tid] = ~rem;
    }
    __syncthreads();

    int c[8]; const int base8 = tid * 8;
    int lsum = 0;
    for (int q = 0; q < 8; ++q) {
        const int i = base8 + q;
        c[q] = (i < PRE_N) ? (int)((keepw32[i >> 5] >> (i & 31)) & 1u) : 0;
        lsum += c[q];
    }
    sscan[tid] = lsum;
    __syncthreads();
    for (int off = 1; off < 256; off <<= 1) {
        int v = (tid >= off) ? sscan[tid - off] : 0;
        __syncthreads();
        sscan[tid] += v;
        __syncthreads();
    }
    const int excl  = sscan[tid] - lsum;
    const int total = sscan[255];

    float* ob  = out + n * POST_N * 4;
    float* osc = out + NIMG * POST_N * 4 + n * POST_N;
    float* ovd = out + NIMG * POST_N * 5 + n * POST_N;

    for (int i = tid; i < POST_N * 4; i += 256) ob[i] = 0.0f;
    for (int i = tid; i < POST_N; i += 256) osc[i] = 0.0f;
    const int lim = min(total, POST_N);
    for (int i = tid; i < POST_N; i += 256) ovd[i] = (i < lim) ? 1.0f : 0.0f;
    __syncthreads();

    int run = excl;
    for (int q = 0; q < 8; ++q) {
        const int i = base8 + q;
        if (i < PRE_N && c[q]) {
            if (run < POST_N) {
                float4 b = ((const float4*)wsBoxes)[n * PRE_N + i];
                ob[run * 4 + 0] = b.x;
                ob[run * 4 + 1] = b.y;
                ob[run * 4 + 2] = b.z;
                ob[run * 4 + 3] = b.w;
                osc[run] = wsScores[n * PRE_N + i];
            }
            run++;
        }
    }
}

extern "C" void kernel_launch(void* const* d_in, const int* in_sizes, int n_in,
                              void* d_out, int out_size, void* d_ws, size_t ws_size,
                              hipStream_t stream) {
    const float* obj  = (const float*)d_in[0];
    const float* breg = (const float*)d_in[1];
    // d_in[2] anchors unused (computed inline, exact in f32)
    float* ws        = (float*)d_ws;
    float* wsBoxes   = ws;                      // 64000 floats
    float* wsScores  = ws + 64000;              // 16000 floats
    int*   wsValid   = (int*)(ws + 80000);      // 16000 ints
    uint64_t* wsMask = (uint64_t*)(ws + 96000); // 8*2000*32 u64 = 4.096 MB

    topk_decode<<<NIMG, 1024, 0, stream>>>(obj, breg, wsBoxes, wsScores, wsValid);
    nms_mask<<<NIMG * 32, 512, 0, stream>>>(wsBoxes, wsMask);
    nms_scan_select<<<NIMG, 256, 0, stream>>>(wsBoxes, wsScores, wsValid, wsMask,
                                              (float*)d_out);
}

// Round 5
// 154.181 us; speedup vs baseline: 1.1576x; 1.0869x over previous
//
#include <hip/hip_runtime.h>
#include <math.h>
#include <stdint.h>

#define NIMG   8
#define NA     30000      // H*W*A = 100*100*3
#define NQ4    7500       // NA/4 float4s
#define PRE_N  2000
#define POST_N 1000
#define NMS_TH 0.7f
#define DCLIP  4.135166556742356f   // log(1000/16)
#define IMGF   1600.0f
#define IMGM1  1599.0f
#define CAND_MAX 4096
#define HPITCH 4104       // 4096 + 8: replica bank-spread padding
#define BIG_BIN 64        // bins larger than this use the 2nd-level sub-radix

// ws layout (floats): boxes [8][2000][4] @0, scores [8][2000] @64000,
//   valid(int) [8][2000] @80000, mask(u64) [8][2000][32] @96000.

// ---------------------------------------------------------------------------
// decode + store helper (verified math, unchanged)
// ---------------------------------------------------------------------------
__device__ __forceinline__ void decode_store(
    uint64_t key, unsigned int rank, int n, const float* __restrict__ breg,
    float* __restrict__ wsBoxes, float* __restrict__ wsScores,
    int* __restrict__ wsValid)
{
    unsigned int idx = (unsigned int)key;
    unsigned int k   = ~((unsigned int)(key >> 32));
    unsigned int u   = (k & 0x80000000u) ? (k & 0x7fffffffu) : ~k;
    float logit = __uint_as_float(u);
    float score = 1.0f / (1.0f + expf(-logit));

    int a = idx % 3, t = idx / 3, w = t % 100, h = t / 100;
    const float* bp = breg + n*120000 + (a*4)*10000 + t;
    float dx = bp[0], dy = bp[10000], dw = bp[20000], dh = bp[30000];

    float half = (a == 0) ? 32.0f : ((a == 1) ? 64.0f : 128.0f);
    float cx = w * 16.0f + 8.0f, cy = h * 16.0f + 8.0f;
    float x1 = cx - half, y1 = cy - half, x2 = cx + half, y2 = cy + half;
    float wd = x2 - x1 + 1.0f, hg = y2 - y1 + 1.0f;
    float cxr = x1 + 0.5f * wd, cyr = y1 + 0.5f * hg;
    dw = fminf(dw, DCLIP); dh = fminf(dh, DCLIP);
    float pcx = dx * wd + cxr, pcy = dy * hg + cyr;
    float pw = expf(dw) * wd, ph = expf(dh) * hg;
    float px1 = pcx - 0.5f * pw, py1 = pcy - 0.5f * ph;
    float px2 = pcx + 0.5f * pw - 1.0f, py2 = pcy + 0.5f * ph - 1.0f;
    px1 = fminf(fmaxf(px1, 0.0f), IMGM1);
    px2 = fminf(fmaxf(px2, 0.0f), IMGM1);
    py1 = fminf(fmaxf(py1, 0.0f), IMGM1);
    py2 = fminf(fmaxf(py2, 0.0f), IMGM1);
    float wss = px2 - px1 + 1.0f, hss = py2 - py1 + 1.0f;
    float xc = px1 + wss * 0.5f, yc = py1 + hss * 0.5f;
    int valid = (wss >= 0.0f) && (hss >= 0.0f) && (xc < IMGF) && (yc < IMGF);

    ((float4*)wsBoxes)[n * PRE_N + (int)rank] = make_float4(px1, py1, px2, py2);
    wsScores[n * PRE_N + (int)rank] = score;
    wsValid [n * PRE_N + (int)rank] = valid;
}

__device__ __forceinline__ unsigned int keyof(float f) {
    unsigned int u = __float_as_uint(f);
    return (u & 0x80000000u) ? ~u : (u | 0x80000000u);
}

// ---------------------------------------------------------------------------
// Kernel AB: fused hist + suffix-sum + bin-grouped rank + decode.
// R5: single COMBINED 2nd-level sub-radix for big bins (R3 did it per-bin
// with block barriers per bin -> overhead ate the win). Detect <=16 big bins,
// count all their elems into one 16x256 sub-histogram (key bits 19:12), one
// wave per big bin does the 256-entry exclusive prefix, one pass regroups
// into grp2, final rank scans only the ~5-elem sub-group. 2nd-level tables
// overlay histogram replicas 0..2 (dead after placement) -> no LDS growth.
// ---------------------------------------------------------------------------
__global__ __launch_bounds__(1024) void topk_decode(
    const float* __restrict__ obj, const float* __restrict__ breg,
    float* __restrict__ wsBoxes, float* __restrict__ wsScores,
    int* __restrict__ wsValid)
{
    const int n    = blockIdx.x;
    const int tid  = threadIdx.x;
    const int lane = tid & 63;
    const int wid  = tid >> 6;
    const int rep  = wid & 3;

    __shared__ unsigned int   histf[4 * HPITCH]; // counts -> bump bases (~64KB)
    __shared__ unsigned short sufx[4096];        // bin start slots
    __shared__ uint64_t       grp[CAND_MAX];     // bin-grouped keys (32KB)
    __shared__ uint64_t       grp2[CAND_MAX];    // sub-grouped big-bin keys (32KB)
    __shared__ unsigned int   wsum[16];
    __shared__ unsigned int   sbstar;
    __shared__ unsigned int   lbbase[16];        // grp2 region base per big bin
    __shared__ unsigned int   lbcnt, lbtot;

    // overlays on dead histogram replicas (valid only AFTER pass 2):
    unsigned int*   hist2  = histf;                                  // [16*256] u32
    unsigned short* sufx2  = (unsigned short*)(histf + HPITCH);      // [4096] u16
    unsigned char*  bin2lb = (unsigned char*)(histf + 2 * HPITCH);   // [4096] u8

    for (int b = tid; b < 4 * HPITCH; b += 1024) histf[b] = 0u;
    __syncthreads();

    // ---- load this thread's 8 float4s once (8 outstanding loads) -----------
    const float4* obj4 = (const float4*)(obj + n * NA);   // 7500 float4
    float4 v[8];
    #pragma unroll
    for (int kk = 0; kk < 7; ++kk) v[kk] = obj4[tid + kk * 1024];
    v[7] = make_float4(0.f, 0.f, 0.f, 0.f);
    if (tid < NQ4 - 7 * 1024) v[7] = obj4[tid + 7 * 1024];   // 332 tail threads

    // ---- pass 1: replica histogram from registers --------------------------
    #pragma unroll
    for (int kk = 0; kk < 8; ++kk) {
        if (kk == 7 && tid >= NQ4 - 7 * 1024) continue;
        atomicAdd(&histf[rep * HPITCH + (keyof(v[kk].x) >> 20)], 1u);
        atomicAdd(&histf[rep * HPITCH + (keyof(v[kk].y) >> 20)], 1u);
        atomicAdd(&histf[rep * HPITCH + (keyof(v[kk].z) >> 20)], 1u);
        atomicAdd(&histf[rep * HPITCH + (keyof(v[kk].w) >> 20)], 1u);
    }
    __syncthreads();

    // ---- suffix-scan of totals (verified structure), bump-base conversion --
    unsigned int c0, c1, c2, c3;
    {
        const int b0 = tid * 4;
        c0 = histf[b0+0] + histf[HPITCH+b0+0] + histf[2*HPITCH+b0+0] + histf[3*HPITCH+b0+0];
        c1 = histf[b0+1] + histf[HPITCH+b0+1] + histf[2*HPITCH+b0+1] + histf[3*HPITCH+b0+1];
        c2 = histf[b0+2] + histf[HPITCH+b0+2] + histf[2*HPITCH+b0+2] + histf[3*HPITCH+b0+2];
        c3 = histf[b0+3] + histf[HPITCH+b0+3] + histf[2*HPITCH+b0+3] + histf[3*HPITCH+b0+3];
    }
    unsigned int p = c0 + c1 + c2 + c3;
    unsigned int s = p;
    #pragma unroll
    for (int off = 1; off < 64; off <<= 1) {
        unsigned int vv = __shfl_down(s, off);
        if (lane + off < 64) s += vv;
    }
    if (lane == 0) wsum[wid] = s;
    __syncthreads();
    unsigned int wafter = 0;
    for (int w = wid + 1; w < 16; ++w) wafter += wsum[w];
    unsigned int after = (s - p) + wafter;   // elems in bins > 4t+3
    {
        unsigned int S3 = after + c3;        // elems in bins > 4t+2
        unsigned int S2 = S3 + c2;           // elems in bins > 4t+1
        unsigned int S1 = S2 + c1;           // elems in bins > 4t+0
        unsigned int S0 = S1 + c0;
        if (S3 >= PRE_N && after < PRE_N) { sbstar = tid*4+3; }
        if (S2 >= PRE_N && S3    < PRE_N) { sbstar = tid*4+2; }
        if (S1 >= PRE_N && S2    < PRE_N) { sbstar = tid*4+1; }
        if (S0 >= PRE_N && S1    < PRE_N) { sbstar = tid*4+0; }
        sufx[tid*4+0] = (unsigned short)S1;
        sufx[tid*4+1] = (unsigned short)S2;
        sufx[tid*4+2] = (unsigned short)S3;
        sufx[tid*4+3] = (unsigned short)after;

        // counts -> per-replica bump bases (each thread touches only own bins)
        const unsigned int st[4] = {S1, S2, S3, after};
        #pragma unroll
        for (int q = 0; q < 4; ++q) {
            const int b = tid*4 + q;
            unsigned int base = st[q];
            #pragma unroll
            for (int r = 0; r < 4; ++r) {
                unsigned int c = histf[r * HPITCH + b];
                histf[r * HPITCH + b] = base;
                base += c;
            }
        }
    }
    __syncthreads();
    const unsigned int bstar = sbstar;

    // ---- pass 2: bin-grouped placement from registers ----------------------
    #pragma unroll
    for (int kk = 0; kk < 8; ++kk) {
        if (kk == 7 && tid >= NQ4 - 7 * 1024) continue;
        const float fv[4] = {v[kk].x, v[kk].y, v[kk].z, v[kk].w};
        #pragma unroll
        for (int e = 0; e < 4; ++e) {
            unsigned int k = keyof(fv[e]);
            unsigned int b = k >> 20;
            if (b < bstar) continue;
            int j = (tid + kk * 1024) * 4 + e;
            int a = j / 10000, t = j - a * 10000;
            uint64_t key = (((uint64_t)(~k)) << 32) | (unsigned int)(t * 3 + a);
            unsigned int slot = atomicAdd(&histf[rep * HPITCH + b], 1u);
            if (slot < CAND_MAX) grp[slot] = key;
        }
    }
    __syncthreads();

    // after pass2, histf[3][b] = end of bin b's slot region (replica 3 stays live)
    const unsigned int total = min(histf[3 * HPITCH + bstar], (unsigned int)CAND_MAX);

    // ---- init overlays (replicas 0..2 now dead) ----------------------------
    ((unsigned int*)bin2lb)[tid] = 0xFFFFFFFFu;              // 4096 B
    hist2[tid] = 0u; hist2[tid+1024] = 0u; hist2[tid+2048] = 0u; hist2[tid+3072] = 0u;
    if (tid == 0) { lbcnt = 0u; lbtot = 0u; }
    __syncthreads();

    // ---- detect big bins (each thread owns bins 4t..4t+3) ------------------
    #pragma unroll
    for (int q = 0; q < 4; ++q) {
        const unsigned int b = (unsigned int)(tid*4 + q);
        if (b >= bstar) {
            const unsigned int ge  = min(histf[3*HPITCH + b], (unsigned int)CAND_MAX);
            const unsigned int cnt = ge - (unsigned int)sufx[b];
            if (cnt > (unsigned int)BIG_BIN) {
                unsigned int pos = atomicAdd(&lbcnt, 1u);
                if (pos < 16u) {
                    bin2lb[b] = (unsigned char)pos;
                    lbbase[pos] = atomicAdd(&lbtot, cnt);
                }
            }
        }
    }
    __syncthreads();

    // ---- count pass: sub-histogram on key bits 19:12 of hi(=~k) ------------
    for (unsigned int slot = tid; slot < total; slot += 1024) {
        const unsigned int hi = (unsigned int)(grp[slot] >> 32);
        const unsigned int b  = 4095u - (hi >> 20);
        const unsigned char lb = bin2lb[b];
        if (lb != 0xFFu)
            atomicAdd(&hist2[(unsigned int)lb * 256u + ((hi >> 12) & 0xFFu)], 1u);
    }
    __syncthreads();

    // ---- per-big-bin 256-entry exclusive prefix: wave w <-> big bin w ------
    {
        const unsigned int nlb = min(lbcnt, 16u);
        if ((unsigned int)wid < nlb) {
            const int xb = wid * 256 + lane * 4;
            unsigned int e0 = hist2[xb+0], e1 = hist2[xb+1],
                         e2 = hist2[xb+2], e3 = hist2[xb+3];
            unsigned int tsum = e0 + e1 + e2 + e3;
            unsigned int inc = tsum;
            #pragma unroll
            for (int off = 1; off < 64; off <<= 1) {
                unsigned int vv = __shfl_up(inc, off);
                if (lane >= off) inc += vv;
            }
            unsigned int base = lbbase[wid] + (inc - tsum);
            hist2[xb+0] = base;             sufx2[xb+0] = (unsigned short)base;
            base += e0; hist2[xb+1] = base; sufx2[xb+1] = (unsigned short)base;
            base += e1; hist2[xb+2] = base; sufx2[xb+2] = (unsigned short)base;
            base += e2; hist2[xb+3] = base; sufx2[xb+3] = (unsigned short)base;
        }
    }
    __syncthreads();

    // ---- regroup big-bin elems into grp2 (bump on hist2) -------------------
    for (unsigned int slot = tid; slot < total; slot += 1024) {
        const uint64_t key = grp[slot];
        const unsigned int hi = (unsigned int)(key >> 32);
        const unsigned int b  = 4095u - (hi >> 20);
        const unsigned char lb = bin2lb[b];
        if (lb != 0xFFu) {
            unsigned int d = atomicAdd(&hist2[(unsigned int)lb * 256u + ((hi >> 12) & 0xFFu)], 1u);
            grp2[d] = key;
        }
    }
    __syncthreads();

    // ---- final: rank + decode ----------------------------------------------
    for (unsigned int slot = tid; slot < total; slot += 1024) {
        const uint64_t key = grp[slot];
        const unsigned int hi = (unsigned int)(key >> 32);   // = ~k
        const unsigned int b  = 4095u - (hi >> 20);
        const unsigned int gbeg = sufx[b];
        const unsigned int gend = min(histf[3 * HPITCH + b], (unsigned int)CAND_MAX);
        const unsigned char lb  = bin2lb[b];
        unsigned int rank;

        if (lb != 0xFFu) {
            // big bin: sub-group scan (avg ~5 elems), predicated 8-wide
            const unsigned int x   = (unsigned int)lb * 256u + ((hi >> 12) & 0xFFu);
            const unsigned int s2  = sufx2[x];
            const unsigned int e2v = hist2[x];     // post-bump = sub-group end
            rank = gbeg + (s2 - lbbase[lb]);
            for (unsigned int g = s2; g < e2v; g += 8u) {
                #pragma unroll
                for (int i = 0; i < 8; ++i) {
                    const unsigned int gi = g + (unsigned int)i;
                    const uint64_t vv = grp2[min(gi, e2v - 1u)];
                    rank += (gi < e2v && vv < key) ? 1u : 0u;
                }
            }
        } else {
            // small bin: 8-wide unrolled scan over grp
            rank = gbeg;
            unsigned int g = gbeg;
            for (; g + 8u <= gend; g += 8u) {
                uint64_t v0 = grp[g+0], v1 = grp[g+1], v2 = grp[g+2], v3 = grp[g+3];
                uint64_t v4 = grp[g+4], v5 = grp[g+5], v6 = grp[g+6], v7 = grp[g+7];
                unsigned int r0 = (v0 < key) ? 1u : 0u;
                r0 += (v1 < key) ? 1u : 0u;
                r0 += (v2 < key) ? 1u : 0u;
                r0 += (v3 < key) ? 1u : 0u;
                r0 += (v4 < key) ? 1u : 0u;
                r0 += (v5 < key) ? 1u : 0u;
                r0 += (v6 < key) ? 1u : 0u;
                r0 += (v7 < key) ? 1u : 0u;
                rank += r0;
            }
            for (; g < gend; ++g)
                rank += (grp[g] < key) ? 1u : 0u;
        }
        if (rank >= PRE_N) continue;
        decode_store(key, rank, n, breg, wsBoxes, wsScores, wsValid);
    }
}

// ---------------------------------------------------------------------------
// Kernel C (verified R11, unchanged): div-free IoU predicate, ballot mask
// word, LDS-staged contiguous store. One block (8 waves) per row-tile.
// ---------------------------------------------------------------------------
__global__ __launch_bounds__(512) void nms_mask(
    const float* __restrict__ wsBoxes, uint64_t* __restrict__ mask)
{
    const int blk  = blockIdx.x;
    const int n    = blk >> 5;
    const int i_t  = blk & 31;
    const int tid  = threadIdx.x;
    const int lane = tid & 63;
    const int wv   = tid >> 6;   // 0..7

    __shared__ uint64_t tile[64 * 33];   // padded pitch 33

    for (int idx = tid; idx < 64 * 33; idx += 512) tile[idx] = 0ull;
    __syncthreads();

    const int r = i_t * 64 + lane;
    float4 rb = (r < PRE_N) ? ((const float4*)wsBoxes)[n * PRE_N + r]
                            : make_float4(0.f, 0.f, 0.f, 0.f);
    float ra = (rb.z - rb.x + 1.0f) * (rb.w - rb.y + 1.0f);

    for (int j_t = i_t + wv; j_t < 32; j_t += 8) {
        const int j = j_t * 64 + lane;
        float4 cb = (j < PRE_N) ? ((const float4*)wsBoxes)[n * PRE_N + j]
                                : make_float4(3e30f, 3e30f, 3e30f, 3e30f);
        float ca = (cb.z - cb.x + 1.0f) * (cb.w - cb.y + 1.0f);
        const uint64_t jmask = (j_t == 31) ? 0xFFFFull : ~0ull;
        const bool diag = (j_t == i_t);
        uint64_t myword = 0ull;

        #pragma unroll
        for (int c = 0; c < 64; ++c) {
            float rx1 = __int_as_float(__builtin_amdgcn_readlane(__float_as_int(rb.x), c));
            float ry1 = __int_as_float(__builtin_amdgcn_readlane(__float_as_int(rb.y), c));
            float rx2 = __int_as_float(__builtin_amdgcn_readlane(__float_as_int(rb.z), c));
            float ry2 = __int_as_float(__builtin_amdgcn_readlane(__float_as_int(rb.w), c));
            float rar = __int_as_float(__builtin_amdgcn_readlane(__float_as_int(ra), c));
            float xx1 = fmaxf(rx1, cb.x), yy1 = fmaxf(ry1, cb.y);
            float xx2 = fminf(rx2, cb.z), yy2 = fminf(ry2, cb.w);
            float ww = fmaxf(xx2 - xx1 + 1.0f, 0.0f);
            float hh = fmaxf(yy2 - yy1 + 1.0f, 0.0f);
            float inter = ww * hh;
            float denom = rar + ca - inter;
            unsigned long long bits = __ballot(inter > NMS_TH * denom) & jmask;
            if (diag) bits &= (c == 63) ? 0ull : ((~0ull) << (c + 1));
            if (lane == c) myword = bits;
        }
        tile[lane * 33 + j_t] = myword;
    }
    __syncthreads();

    uint64_t* mrow = mask + ((size_t)n * PRE_N + (size_t)i_t * 64) * 32;
    const int cmax = (i_t == 31) ? 16 : 64;
    for (int idx = tid; idx < cmax * 32; idx += 512) {
        const int rr = idx >> 5, w = idx & 31;
        mrow[idx] = tile[rr * 33 + w];
    }
}

// ---------------------------------------------------------------------------
// Kernel D (verified R8, unchanged): serial greedy scan, inline asm, 64-slot
// VGPR ring, pure-SALU chain, early-exit at kept=1000.
// ---------------------------------------------------------------------------
#define SL(n,b) \
    "global_load_dword v" #n ", %[voff], %[sbase]\n\t" \
    "v_add_u32 %[voff], 0x100, %[voff]\n\t"

#define SS(n,b) \
    "s_waitcnt vmcnt(63)\n\t" \
    "v_readlane_b32 %[t], v" #n ", %[lw]\n\t" \
    "s_bitcmp1_b32 %[win], " #b "\n\t" \
    "s_cselect_b32 %[m], 0, -1\n\t" \
    "s_sub_i32 %[kept], %[kept], %[m]\n\t" \
    "s_and_b32 %[t], %[t], %[m]\n\t" \
    "s_or_b32 %[win], %[win], %[t]\n\t" \
    "v_and_b32 v" #n ", %[m], v" #n "\n\t" \
    "v_or_b32 %[rem], %[rem], v" #n "\n\t" \
    "global_load_dword v" #n ", %[voff], %[sbase]\n\t" \
    "v_add_u32 %[voff], 0x100, %[voff]\n\t"

#define SN(n,b,w) \
    "s_waitcnt vmcnt(" #w ")\n\t" \
    "v_readlane_b32 %[t], v" #n ", %[lw]\n\t" \
    "s_bitcmp1_b32 %[win], " #b "\n\t" \
    "s_cselect_b32 %[m], 0, -1\n\t" \
    "s_sub_i32 %[kept], %[kept], %[m]\n\t" \
    "s_and_b32 %[t], %[t], %[m]\n\t" \
    "s_or_b32 %[win], %[win], %[t]\n\t" \
    "v_and_b32 v" #n ", %[m], v" #n "\n\t" \
    "v_or_b32 %[rem], %[rem], v" #n "\n\t"

#define SWIN \
    "s_add_u32 %[lw], %[lw], 1\n\t" \
    "v_readlane_b32 %[t], %[rem], %[lw]\n\t" \
    "s_mov_b32 %[win], %[t]\n\t"

#define ROW_A(M) M(64,0) M(65,1) M(66,2) M(67,3) M(68,4) M(69,5) M(70,6) M(71,7) \
    M(72,8) M(73,9) M(74,10) M(75,11) M(76,12) M(77,13) M(78,14) M(79,15) \
    M(80,16) M(81,17) M(82,18) M(83,19) M(84,20) M(85,21) M(86,22) M(87,23) \
    M(88,24) M(89,25) M(90,26) M(91,27) M(92,28) M(93,29) M(94,30) M(95,31)
#define ROW_B(M) M(96,0) M(97,1) M(98,2) M(99,3) M(100,4) M(101,5) M(102,6) M(103,7) \
    M(104,8) M(105,9) M(106,10) M(107,11) M(108,12) M(109,13) M(110,14) M(111,15) \
    M(112,16) M(113,17) M(114,18) M(115,19) M(116,20) M(117,21) M(118,22) M(119,23) \
    M(120,24) M(121,25) M(122,26) M(123,27) M(124,28) M(125,29) M(126,30) M(127,31)

__global__ __launch_bounds__(256) void nms_scan_select(
    const float* __restrict__ wsBoxes, const float* __restrict__ wsScores,
    const int* __restrict__ wsValid, const uint64_t* __restrict__ mask,
    float* __restrict__ out)
{
    const int n   = blockIdx.x;
    const int tid = threadIdx.x;

    __shared__ __align__(8) unsigned char invb[256];
    __shared__ unsigned int keepw32[64];
    __shared__ int sscan[256];

    unsigned int byte = 0xFFu;
    if (tid < PRE_N / 8) {
        byte = 0u;
        for (int q = 0; q < 8; ++q)
            byte |= (wsValid[n * PRE_N + tid * 8 + q] ? 0u : 1u) << q;
    }
    invb[tid] = (unsigned char)byte;
    __syncthreads();

    if (tid < 64) {
        unsigned int rem = ((const unsigned int*)invb)[tid];
        unsigned long long sbase =
            (unsigned long long)(const void*)(mask + (size_t)n * PRE_N * 32);
        unsigned int voff = (unsigned int)(tid * 4);
        int win_, m_, t_, lw_, kept_, cnt_;

        asm volatile(
            "s_waitcnt vmcnt(0) lgkmcnt(0)\n\t"
            "s_mov_b32 %[kept], 0\n\t"
            "s_mov_b32 %[lw], 0\n\t"
            ROW_A(SL) ROW_B(SL)
            "v_readlane_b32 %[t], %[rem], %[lw]\n\t"
            "s_mov_b32 %[win], %[t]\n\t"
            "s_mov_b32 %[cnt], 30\n\t"
            "Lnms_%=:\n\t"
            ROW_A(SS)
            SWIN
            ROW_B(SS)
            SWIN
            "s_cmp_ge_i32 %[kept], 0x3e8\n\t"
            "s_cbranch_scc1 Lend_%=\n\t"
            "s_sub_u32 %[cnt], %[cnt], 1\n\t"
            "s_cmp_lg_u32 %[cnt], 0\n\t"
            "s_cbranch_scc1 Lnms_%=\n\t"
            SS(64,0) SS(65,1) SS(66,2) SS(67,3) SS(68,4) SS(69,5) SS(70,6) SS(71,7)
            SS(72,8) SS(73,9) SS(74,10) SS(75,11) SS(76,12) SS(77,13) SS(78,14) SS(79,15)
            SN(80,16,63) SN(81,17,62) SN(82,18,61) SN(83,19,60)
            SN(84,20,59) SN(85,21,58) SN(86,22,57) SN(87,23,56)
            SN(88,24,55) SN(89,25,54) SN(90,26,53) SN(91,27,52)
            SN(92,28,51) SN(93,29,50) SN(94,30,49) SN(95,31,48)
            SWIN
            SN(96,0,47) SN(97,1,46) SN(98,2,45) SN(99,3,44)
            SN(100,4,43) SN(101,5,42) SN(102,6,41) SN(103,7,40)
            SN(104,8,39) SN(105,9,38) SN(106,10,37) SN(107,11,36)
            SN(108,12,35) SN(109,13,34) SN(110,14,33) SN(111,15,32)
            SN(112,16,31) SN(113,17,30) SN(114,18,29) SN(115,19,28)
            SN(116,20,27) SN(117,21,26) SN(118,22,25) SN(119,23,24)
            SN(120,24,23) SN(121,25,22) SN(122,26,21) SN(123,27,20)
            SN(124,28,19) SN(125,29,18) SN(126,30,17) SN(127,31,16)
            SWIN
            SN(64,0,15) SN(65,1,14) SN(66,2,13) SN(67,3,12)
            SN(68,4,11) SN(69,5,10) SN(70,6,9) SN(71,7,8)
            SN(72,8,7) SN(73,9,6) SN(74,10,5) SN(75,11,4)
            SN(76,12,3) SN(77,13,2) SN(78,14,1) SN(79,15,0)
            "Lend_%=:\n\t"
            "s_waitcnt vmcnt(0)\n\t"
            : [rem]"+v"(rem), [voff]"+v"(voff),
              [win]"=&s"(win_), [m]"=&s"(m_), [t]"=&s"(t_),
              [lw]"=&s"(lw_), [kept]"=&s"(kept_), [cnt]"=&s"(cnt_)
            : [sbase]"s"(sbase)
            : "scc", "vcc", "memory",
              "v64","v65","v66","v67","v68","v69","v70","v71",
              "v72","v73","v74","v75","v76","v77","v78","v79",
              "v80","v81","v82","v83","v84","v85","v86","v87",
              "v88","v89","v90","v91","v92","v93","v94","v95",
              "v96","v97","v98","v99","v100","v101","v102","v103",
              "v104","v105","v106","v107","v108","v109","v110","v111",
              "v112","v113","v114","v115","v116","v117","v118","v119",
              "v120","v121","v122","v123","v124","v125","v126","v127");

        keepw32[tid] = ~rem;
    }
    __syncthreads();

    int c[8]; const int base8 = tid * 8;
    int lsum = 0;
    for (int q = 0; q < 8; ++q) {
        const int i = base8 + q;
        c[q] = (i < PRE_N) ? (int)((keepw32[i >> 5] >> (i & 31)) & 1u) : 0;
        lsum += c[q];
    }
    sscan[tid] = lsum;
    __syncthreads();
    for (int off = 1; off < 256; off <<= 1) {
        int v = (tid >= off) ? sscan[tid - off] : 0;
        __syncthreads();
        sscan[tid] += v;
        __syncthreads();
    }
    const int excl  = sscan[tid] - lsum;
    const int total = sscan[255];

    float* ob  = out + n * POST_N * 4;
    float* osc = out + NIMG * POST_N * 4 + n * POST_N;
    float* ovd = out + NIMG * POST_N * 5 + n * POST_N;

    for (int i = tid; i < POST_N * 4; i += 256) ob[i] = 0.0f;
    for (int i = tid; i < POST_N; i += 256) osc[i] = 0.0f;
    const int lim = min(total, POST_N);
    for (int i = tid; i < POST_N; i += 256) ovd[i] = (i < lim) ? 1.0f : 0.0f;
    __syncthreads();

    int run = excl;
    for (int q = 0; q < 8; ++q) {
        const int i = base8 + q;
        if (i < PRE_N && c[q]) {
            if (run < POST_N) {
                float4 b = ((const float4*)wsBoxes)[n * PRE_N + i];
                ob[run * 4 + 0] = b.x;
                ob[run * 4 + 1] = b.y;
                ob[run * 4 + 2] = b.z;
                ob[run * 4 + 3] = b.w;
                osc[run] = wsScores[n * PRE_N + i];
            }
            run++;
        }
    }
}

extern "C" void kernel_launch(void* const* d_in, const int* in_sizes, int n_in,
                              void* d_out, int out_size, void* d_ws, size_t ws_size,
                              hipStream_t stream) {
    const float* obj  = (const float*)d_in[0];
    const float* breg = (const float*)d_in[1];
    // d_in[2] anchors unused (computed inline, exact in f32)
    float* ws        = (float*)d_ws;
    float* wsBoxes   = ws;                      // 64000 floats
    float* wsScores  = ws + 64000;              // 16000 floats
    int*   wsValid   = (int*)(ws + 80000);      // 16000 ints
    uint64_t* wsMask = (uint64_t*)(ws + 96000); // 8*2000*32 u64 = 4.096 MB

    topk_decode<<<NIMG, 1024, 0, stream>>>(obj, breg, wsBoxes, wsScores, wsValid);
    nms_mask<<<NIMG * 32, 512, 0, stream>>>(wsBoxes, wsMask);
    nms_scan_select<<<NIMG, 256, 0, stream>>>(wsBoxes, wsScores, wsValid, wsMask,
                                              (float*)d_out);
}

// Round 6
// 153.000 us; speedup vs baseline: 1.1665x; 1.0077x over previous
//
#include <hip/hip_runtime.h>
#include <math.h>
#include <stdint.h>

#define NIMG   8
#define NA     30000      // H*W*A = 100*100*3
#define NQ4    7500       // NA/4 float4s
#define PRE_N  2000
#define POST_N 1000
#define NMS_TH 0.7f
#define DCLIP  4.135166556742356f   // log(1000/16)
#define IMGF   1600.0f
#define IMGM1  1599.0f
#define CAND_MAX 4096
#define HPITCH 4104       // 4096 + 8: replica bank-spread padding
#define BIG_BIN 64        // bins larger than this use the 2nd-level sub-radix
#define PREF_BIN 3064u    // keyof(1.0f)>>20: pass-1 prefilter pivot (fallback-safe)

// ws layout (floats): boxes [8][2000][4] @0, scores [8][2000] @64000,
//   valid(int) [8][2000] @80000, mask(u64) [8][2000][32] @96000.

// ---------------------------------------------------------------------------
// decode + store helper (verified math, unchanged)
// ---------------------------------------------------------------------------
__device__ __forceinline__ void decode_store(
    uint64_t key, unsigned int rank, int n, const float* __restrict__ breg,
    float* __restrict__ wsBoxes, float* __restrict__ wsScores,
    int* __restrict__ wsValid)
{
    unsigned int idx = (unsigned int)key;
    unsigned int k   = ~((unsigned int)(key >> 32));
    unsigned int u   = (k & 0x80000000u) ? (k & 0x7fffffffu) : ~k;
    float logit = __uint_as_float(u);
    float score = 1.0f / (1.0f + expf(-logit));

    int a = idx % 3, t = idx / 3, w = t % 100, h = t / 100;
    const float* bp = breg + n*120000 + (a*4)*10000 + t;
    float dx = bp[0], dy = bp[10000], dw = bp[20000], dh = bp[30000];

    float half = (a == 0) ? 32.0f : ((a == 1) ? 64.0f : 128.0f);
    float cx = w * 16.0f + 8.0f, cy = h * 16.0f + 8.0f;
    float x1 = cx - half, y1 = cy - half, x2 = cx + half, y2 = cy + half;
    float wd = x2 - x1 + 1.0f, hg = y2 - y1 + 1.0f;
    float cxr = x1 + 0.5f * wd, cyr = y1 + 0.5f * hg;
    dw = fminf(dw, DCLIP); dh = fminf(dh, DCLIP);
    float pcx = dx * wd + cxr, pcy = dy * hg + cyr;
    float pw = expf(dw) * wd, ph = expf(dh) * hg;
    float px1 = pcx - 0.5f * pw, py1 = pcy - 0.5f * ph;
    float px2 = pcx + 0.5f * pw - 1.0f, py2 = pcy + 0.5f * ph - 1.0f;
    px1 = fminf(fmaxf(px1, 0.0f), IMGM1);
    px2 = fminf(fmaxf(px2, 0.0f), IMGM1);
    py1 = fminf(fmaxf(py1, 0.0f), IMGM1);
    py2 = fminf(fmaxf(py2, 0.0f), IMGM1);
    float wss = px2 - px1 + 1.0f, hss = py2 - py1 + 1.0f;
    float xc = px1 + wss * 0.5f, yc = py1 + hss * 0.5f;
    int valid = (wss >= 0.0f) && (hss >= 0.0f) && (xc < IMGF) && (yc < IMGF);

    ((float4*)wsBoxes)[n * PRE_N + (int)rank] = make_float4(px1, py1, px2, py2);
    wsScores[n * PRE_N + (int)rank] = score;
    wsValid [n * PRE_N + (int)rank] = valid;
}

__device__ __forceinline__ unsigned int keyof(float f) {
    unsigned int u = __float_as_uint(f);
    return (u & 0x80000000u) ? ~u : (u | 0x80000000u);
}

// ---------------------------------------------------------------------------
// Kernel AB: fused hist + suffix-sum + bin-grouped rank + decode.
// R6: pass-1 prefilter — bstar only depends on counts of bins ABOVE the
// 2000th element's bin, so keys in bins < PREF_BIN (logit < 1.0) are skipped
// in the histogram: ~30k -> ~4.7k LDS atomics. Block-uniform fallback tops
// up the histogram with the skipped keys if the filtered total < PRE_N
// (never taken for Gaussian logits; required for arbitrary inputs).
// ---------------------------------------------------------------------------
__global__ __launch_bounds__(1024) void topk_decode(
    const float* __restrict__ obj, const float* __restrict__ breg,
    float* __restrict__ wsBoxes, float* __restrict__ wsScores,
    int* __restrict__ wsValid)
{
    const int n    = blockIdx.x;
    const int tid  = threadIdx.x;
    const int lane = tid & 63;
    const int wid  = tid >> 6;
    const int rep  = wid & 3;

    __shared__ unsigned int   histf[4 * HPITCH]; // counts -> bump bases (~64KB)
    __shared__ unsigned short sufx[4096];        // bin start slots
    __shared__ uint64_t       grp[CAND_MAX];     // bin-grouped keys (32KB)
    __shared__ uint64_t       grp2[CAND_MAX];    // sub-grouped big-bin keys (32KB)
    __shared__ unsigned int   wsum[16];
    __shared__ unsigned int   sbstar;
    __shared__ unsigned int   lbbase[16];        // grp2 region base per big bin
    __shared__ unsigned int   lbcnt, lbtot;

    // overlays on dead histogram replicas (valid only AFTER pass 2):
    unsigned int*   hist2  = histf;                                  // [16*256] u32
    unsigned short* sufx2  = (unsigned short*)(histf + HPITCH);      // [4096] u16
    unsigned char*  bin2lb = (unsigned char*)(histf + 2 * HPITCH);   // [4096] u8

    for (int b = tid; b < 4 * HPITCH; b += 1024) histf[b] = 0u;
    __syncthreads();

    // ---- load this thread's 8 float4s once (8 outstanding loads) -----------
    const float4* obj4 = (const float4*)(obj + n * NA);   // 7500 float4
    float4 v[8];
    #pragma unroll
    for (int kk = 0; kk < 7; ++kk) v[kk] = obj4[tid + kk * 1024];
    v[7] = make_float4(0.f, 0.f, 0.f, 0.f);
    if (tid < NQ4 - 7 * 1024) v[7] = obj4[tid + 7 * 1024];   // 332 tail threads

    // ---- pass 1: prefiltered replica histogram from registers --------------
    #pragma unroll
    for (int kk = 0; kk < 8; ++kk) {
        if (kk == 7 && tid >= NQ4 - 7 * 1024) continue;
        const float fv[4] = {v[kk].x, v[kk].y, v[kk].z, v[kk].w};
        #pragma unroll
        for (int e = 0; e < 4; ++e) {
            unsigned int b = keyof(fv[e]) >> 20;
            if (b >= PREF_BIN)
                atomicAdd(&histf[rep * HPITCH + b], 1u);
        }
    }
    __syncthreads();

    // ---- totals + fallback check -------------------------------------------
    unsigned int c0, c1, c2, c3;
    {
        const int b0 = tid * 4;
        c0 = histf[b0+0] + histf[HPITCH+b0+0] + histf[2*HPITCH+b0+0] + histf[3*HPITCH+b0+0];
        c1 = histf[b0+1] + histf[HPITCH+b0+1] + histf[2*HPITCH+b0+1] + histf[3*HPITCH+b0+1];
        c2 = histf[b0+2] + histf[HPITCH+b0+2] + histf[2*HPITCH+b0+2] + histf[3*HPITCH+b0+2];
        c3 = histf[b0+3] + histf[HPITCH+b0+3] + histf[2*HPITCH+b0+3] + histf[3*HPITCH+b0+3];
    }
    unsigned int p = c0 + c1 + c2 + c3;
    unsigned int s = p;
    #pragma unroll
    for (int off = 1; off < 64; off <<= 1) {
        unsigned int vv = __shfl_down(s, off);
        if (lane + off < 64) s += vv;
    }
    if (lane == 0) wsum[wid] = s;
    __syncthreads();
    unsigned int ftotal = 0;
    for (int w = 0; w < 16; ++w) ftotal += wsum[w];

    if (ftotal < PRE_N) {
        // fallback (block-uniform): top-up with the skipped low bins, redo reduce
        #pragma unroll
        for (int kk = 0; kk < 8; ++kk) {
            if (kk == 7 && tid >= NQ4 - 7 * 1024) continue;
            const float fv[4] = {v[kk].x, v[kk].y, v[kk].z, v[kk].w};
            #pragma unroll
            for (int e = 0; e < 4; ++e) {
                unsigned int b = keyof(fv[e]) >> 20;
                if (b < PREF_BIN)
                    atomicAdd(&histf[rep * HPITCH + b], 1u);
            }
        }
        __syncthreads();
        {
            const int b0 = tid * 4;
            c0 = histf[b0+0] + histf[HPITCH+b0+0] + histf[2*HPITCH+b0+0] + histf[3*HPITCH+b0+0];
            c1 = histf[b0+1] + histf[HPITCH+b0+1] + histf[2*HPITCH+b0+1] + histf[3*HPITCH+b0+1];
            c2 = histf[b0+2] + histf[HPITCH+b0+2] + histf[2*HPITCH+b0+2] + histf[3*HPITCH+b0+2];
            c3 = histf[b0+3] + histf[HPITCH+b0+3] + histf[2*HPITCH+b0+3] + histf[3*HPITCH+b0+3];
        }
        p = c0 + c1 + c2 + c3;
        s = p;
        #pragma unroll
        for (int off = 1; off < 64; off <<= 1) {
            unsigned int vv = __shfl_down(s, off);
            if (lane + off < 64) s += vv;
        }
        __syncthreads();            // wsum reuse
        if (lane == 0) wsum[wid] = s;
        __syncthreads();
    }

    // ---- suffix-scan (verified structure), bump-base conversion ------------
    unsigned int wafter = 0;
    for (int w = wid + 1; w < 16; ++w) wafter += wsum[w];
    unsigned int after = (s - p) + wafter;   // elems in bins > 4t+3
    {
        unsigned int S3 = after + c3;        // elems in bins > 4t+2
        unsigned int S2 = S3 + c2;           // elems in bins > 4t+1
        unsigned int S1 = S2 + c1;           // elems in bins > 4t+0
        unsigned int S0 = S1 + c0;
        if (S3 >= PRE_N && after < PRE_N) { sbstar = tid*4+3; }
        if (S2 >= PRE_N && S3    < PRE_N) { sbstar = tid*4+2; }
        if (S1 >= PRE_N && S2    < PRE_N) { sbstar = tid*4+1; }
        if (S0 >= PRE_N && S1    < PRE_N) { sbstar = tid*4+0; }
        sufx[tid*4+0] = (unsigned short)S1;
        sufx[tid*4+1] = (unsigned short)S2;
        sufx[tid*4+2] = (unsigned short)S3;
        sufx[tid*4+3] = (unsigned short)after;

        // counts -> per-replica bump bases (each thread touches only own bins)
        const unsigned int st[4] = {S1, S2, S3, after};
        #pragma unroll
        for (int q = 0; q < 4; ++q) {
            const int b = tid*4 + q;
            unsigned int base = st[q];
            #pragma unroll
            for (int r = 0; r < 4; ++r) {
                unsigned int c = histf[r * HPITCH + b];
                histf[r * HPITCH + b] = base;
                base += c;
            }
        }
    }
    __syncthreads();
    const unsigned int bstar = sbstar;

    // ---- pass 2: bin-grouped placement from registers ----------------------
    #pragma unroll
    for (int kk = 0; kk < 8; ++kk) {
        if (kk == 7 && tid >= NQ4 - 7 * 1024) continue;
        const float fv[4] = {v[kk].x, v[kk].y, v[kk].z, v[kk].w};
        #pragma unroll
        for (int e = 0; e < 4; ++e) {
            unsigned int k = keyof(fv[e]);
            unsigned int b = k >> 20;
            if (b < bstar) continue;
            int j = (tid + kk * 1024) * 4 + e;
            int a = j / 10000, t = j - a * 10000;
            uint64_t key = (((uint64_t)(~k)) << 32) | (unsigned int)(t * 3 + a);
            unsigned int slot = atomicAdd(&histf[rep * HPITCH + b], 1u);
            if (slot < CAND_MAX) grp[slot] = key;
        }
    }
    __syncthreads();

    // after pass2, histf[3][b] = end of bin b's slot region (replica 3 stays live)
    const unsigned int total = min(histf[3 * HPITCH + bstar], (unsigned int)CAND_MAX);

    // ---- init overlays (replicas 0..2 now dead) ----------------------------
    ((unsigned int*)bin2lb)[tid] = 0xFFFFFFFFu;              // 4096 B
    hist2[tid] = 0u; hist2[tid+1024] = 0u; hist2[tid+2048] = 0u; hist2[tid+3072] = 0u;
    if (tid == 0) { lbcnt = 0u; lbtot = 0u; }
    __syncthreads();

    // ---- detect big bins (each thread owns bins 4t..4t+3) ------------------
    #pragma unroll
    for (int q = 0; q < 4; ++q) {
        const unsigned int b = (unsigned int)(tid*4 + q);
        if (b >= bstar) {
            const unsigned int ge  = min(histf[3*HPITCH + b], (unsigned int)CAND_MAX);
            const unsigned int cnt = ge - (unsigned int)sufx[b];
            if (cnt > (unsigned int)BIG_BIN) {
                unsigned int pos = atomicAdd(&lbcnt, 1u);
                if (pos < 16u) {
                    bin2lb[b] = (unsigned char)pos;
                    lbbase[pos] = atomicAdd(&lbtot, cnt);
                }
            }
        }
    }
    __syncthreads();

    // ---- count pass: sub-histogram on key bits 19:12 of hi(=~k) ------------
    for (unsigned int slot = tid; slot < total; slot += 1024) {
        const unsigned int hi = (unsigned int)(grp[slot] >> 32);
        const unsigned int b  = 4095u - (hi >> 20);
        const unsigned char lb = bin2lb[b];
        if (lb != 0xFFu)
            atomicAdd(&hist2[(unsigned int)lb * 256u + ((hi >> 12) & 0xFFu)], 1u);
    }
    __syncthreads();

    // ---- per-big-bin 256-entry exclusive prefix: wave w <-> big bin w ------
    {
        const unsigned int nlb = min(lbcnt, 16u);
        if ((unsigned int)wid < nlb) {
            const int xb = wid * 256 + lane * 4;
            unsigned int e0 = hist2[xb+0], e1 = hist2[xb+1],
                         e2 = hist2[xb+2], e3 = hist2[xb+3];
            unsigned int tsum = e0 + e1 + e2 + e3;
            unsigned int inc = tsum;
            #pragma unroll
            for (int off = 1; off < 64; off <<= 1) {
                unsigned int vv = __shfl_up(inc, off);
                if (lane >= off) inc += vv;
            }
            unsigned int base = lbbase[wid] + (inc - tsum);
            hist2[xb+0] = base;             sufx2[xb+0] = (unsigned short)base;
            base += e0; hist2[xb+1] = base; sufx2[xb+1] = (unsigned short)base;
            base += e1; hist2[xb+2] = base; sufx2[xb+2] = (unsigned short)base;
            base += e2; hist2[xb+3] = base; sufx2[xb+3] = (unsigned short)base;
        }
    }
    __syncthreads();

    // ---- regroup big-bin elems into grp2 (bump on hist2) -------------------
    for (unsigned int slot = tid; slot < total; slot += 1024) {
        const uint64_t key = grp[slot];
        const unsigned int hi = (unsigned int)(key >> 32);
        const unsigned int b  = 4095u - (hi >> 20);
        const unsigned char lb = bin2lb[b];
        if (lb != 0xFFu) {
            unsigned int d = atomicAdd(&hist2[(unsigned int)lb * 256u + ((hi >> 12) & 0xFFu)], 1u);
            grp2[d] = key;
        }
    }
    __syncthreads();

    // ---- final: rank + decode ----------------------------------------------
    for (unsigned int slot = tid; slot < total; slot += 1024) {
        const uint64_t key = grp[slot];
        const unsigned int hi = (unsigned int)(key >> 32);   // = ~k
        const unsigned int b  = 4095u - (hi >> 20);
        const unsigned int gbeg = sufx[b];
        const unsigned int gend = min(histf[3 * HPITCH + b], (unsigned int)CAND_MAX);
        const unsigned char lb  = bin2lb[b];
        unsigned int rank;

        if (lb != 0xFFu) {
            // big bin: sub-group scan (avg ~5 elems), predicated 8-wide
            const unsigned int x   = (unsigned int)lb * 256u + ((hi >> 12) & 0xFFu);
            const unsigned int s2  = sufx2[x];
            const unsigned int e2v = hist2[x];     // post-bump = sub-group end
            rank = gbeg + (s2 - lbbase[lb]);
            for (unsigned int g = s2; g < e2v; g += 8u) {
                #pragma unroll
                for (int i = 0; i < 8; ++i) {
                    const unsigned int gi = g + (unsigned int)i;
                    const uint64_t vv = grp2[min(gi, e2v - 1u)];
                    rank += (gi < e2v && vv < key) ? 1u : 0u;
                }
            }
        } else {
            // small bin: 8-wide unrolled scan over grp
            rank = gbeg;
            unsigned int g = gbeg;
            for (; g + 8u <= gend; g += 8u) {
                uint64_t v0 = grp[g+0], v1 = grp[g+1], v2 = grp[g+2], v3 = grp[g+3];
                uint64_t v4 = grp[g+4], v5 = grp[g+5], v6 = grp[g+6], v7 = grp[g+7];
                unsigned int r0 = (v0 < key) ? 1u : 0u;
                r0 += (v1 < key) ? 1u : 0u;
                r0 += (v2 < key) ? 1u : 0u;
                r0 += (v3 < key) ? 1u : 0u;
                r0 += (v4 < key) ? 1u : 0u;
                r0 += (v5 < key) ? 1u : 0u;
                r0 += (v6 < key) ? 1u : 0u;
                r0 += (v7 < key) ? 1u : 0u;
                rank += r0;
            }
            for (; g < gend; ++g)
                rank += (grp[g] < key) ? 1u : 0u;
        }
        if (rank >= PRE_N) continue;
        decode_store(key, rank, n, breg, wsBoxes, wsScores, wsValid);
    }
}

// ---------------------------------------------------------------------------
// Kernel C (verified R11, unchanged): div-free IoU predicate, ballot mask
// word, LDS-staged contiguous store. One block (8 waves) per row-tile.
// ---------------------------------------------------------------------------
__global__ __launch_bounds__(512) void nms_mask(
    const float* __restrict__ wsBoxes, uint64_t* __restrict__ mask)
{
    const int blk  = blockIdx.x;
    const int n    = blk >> 5;
    const int i_t  = blk & 31;
    const int tid  = threadIdx.x;
    const int lane = tid & 63;
    const int wv   = tid >> 6;   // 0..7

    __shared__ uint64_t tile[64 * 33];   // padded pitch 33

    for (int idx = tid; idx < 64 * 33; idx += 512) tile[idx] = 0ull;
    __syncthreads();

    const int r = i_t * 64 + lane;
    float4 rb = (r < PRE_N) ? ((const float4*)wsBoxes)[n * PRE_N + r]
                            : make_float4(0.f, 0.f, 0.f, 0.f);
    float ra = (rb.z - rb.x + 1.0f) * (rb.w - rb.y + 1.0f);

    for (int j_t = i_t + wv; j_t < 32; j_t += 8) {
        const int j = j_t * 64 + lane;
        float4 cb = (j < PRE_N) ? ((const float4*)wsBoxes)[n * PRE_N + j]
                                : make_float4(3e30f, 3e30f, 3e30f, 3e30f);
        float ca = (cb.z - cb.x + 1.0f) * (cb.w - cb.y + 1.0f);
        const uint64_t jmask = (j_t == 31) ? 0xFFFFull : ~0ull;
        const bool diag = (j_t == i_t);
        uint64_t myword = 0ull;

        #pragma unroll
        for (int c = 0; c < 64; ++c) {
            float rx1 = __int_as_float(__builtin_amdgcn_readlane(__float_as_int(rb.x), c));
            float ry1 = __int_as_float(__builtin_amdgcn_readlane(__float_as_int(rb.y), c));
            float rx2 = __int_as_float(__builtin_amdgcn_readlane(__float_as_int(rb.z), c));
            float ry2 = __int_as_float(__builtin_amdgcn_readlane(__float_as_int(rb.w), c));
            float rar = __int_as_float(__builtin_amdgcn_readlane(__float_as_int(ra), c));
            float xx1 = fmaxf(rx1, cb.x), yy1 = fmaxf(ry1, cb.y);
            float xx2 = fminf(rx2, cb.z), yy2 = fminf(ry2, cb.w);
            float ww = fmaxf(xx2 - xx1 + 1.0f, 0.0f);
            float hh = fmaxf(yy2 - yy1 + 1.0f, 0.0f);
            float inter = ww * hh;
            float denom = rar + ca - inter;
            unsigned long long bits = __ballot(inter > NMS_TH * denom) & jmask;
            if (diag) bits &= (c == 63) ? 0ull : ((~0ull) << (c + 1));
            if (lane == c) myword = bits;
        }
        tile[lane * 33 + j_t] = myword;
    }
    __syncthreads();

    uint64_t* mrow = mask + ((size_t)n * PRE_N + (size_t)i_t * 64) * 32;
    const int cmax = (i_t == 31) ? 16 : 64;
    for (int idx = tid; idx < cmax * 32; idx += 512) {
        const int rr = idx >> 5, w = idx & 31;
        mrow[idx] = tile[rr * 33 + w];
    }
}

// ---------------------------------------------------------------------------
// Kernel D (verified R8, unchanged): serial greedy scan, inline asm, 64-slot
// VGPR ring, pure-SALU chain, early-exit at kept=1000.
// ---------------------------------------------------------------------------
#define SL(n,b) \
    "global_load_dword v" #n ", %[voff], %[sbase]\n\t" \
    "v_add_u32 %[voff], 0x100, %[voff]\n\t"

#define SS(n,b) \
    "s_waitcnt vmcnt(63)\n\t" \
    "v_readlane_b32 %[t], v" #n ", %[lw]\n\t" \
    "s_bitcmp1_b32 %[win], " #b "\n\t" \
    "s_cselect_b32 %[m], 0, -1\n\t" \
    "s_sub_i32 %[kept], %[kept], %[m]\n\t" \
    "s_and_b32 %[t], %[t], %[m]\n\t" \
    "s_or_b32 %[win], %[win], %[t]\n\t" \
    "v_and_b32 v" #n ", %[m], v" #n "\n\t" \
    "v_or_b32 %[rem], %[rem], v" #n "\n\t" \
    "global_load_dword v" #n ", %[voff], %[sbase]\n\t" \
    "v_add_u32 %[voff], 0x100, %[voff]\n\t"

#define SN(n,b,w) \
    "s_waitcnt vmcnt(" #w ")\n\t" \
    "v_readlane_b32 %[t], v" #n ", %[lw]\n\t" \
    "s_bitcmp1_b32 %[win], " #b "\n\t" \
    "s_cselect_b32 %[m], 0, -1\n\t" \
    "s_sub_i32 %[kept], %[kept], %[m]\n\t" \
    "s_and_b32 %[t], %[t], %[m]\n\t" \
    "s_or_b32 %[win], %[win], %[t]\n\t" \
    "v_and_b32 v" #n ", %[m], v" #n "\n\t" \
    "v_or_b32 %[rem], %[rem], v" #n "\n\t"

#define SWIN \
    "s_add_u32 %[lw], %[lw], 1\n\t" \
    "v_readlane_b32 %[t], %[rem], %[lw]\n\t" \
    "s_mov_b32 %[win], %[t]\n\t"

#define ROW_A(M) M(64,0) M(65,1) M(66,2) M(67,3) M(68,4) M(69,5) M(70,6) M(71,7) \
    M(72,8) M(73,9) M(74,10) M(75,11) M(76,12) M(77,13) M(78,14) M(79,15) \
    M(80,16) M(81,17) M(82,18) M(83,19) M(84,20) M(85,21) M(86,22) M(87,23) \
    M(88,24) M(89,25) M(90,26) M(91,27) M(92,28) M(93,29) M(94,30) M(95,31)
#define ROW_B(M) M(96,0) M(97,1) M(98,2) M(99,3) M(100,4) M(101,5) M(102,6) M(103,7) \
    M(104,8) M(105,9) M(106,10) M(107,11) M(108,12) M(109,13) M(110,14) M(111,15) \
    M(112,16) M(113,17) M(114,18) M(115,19) M(116,20) M(117,21) M(118,22) M(119,23) \
    M(120,24) M(121,25) M(122,26) M(123,27) M(124,28) M(125,29) M(126,30) M(127,31)

__global__ __launch_bounds__(256) void nms_scan_select(
    const float* __restrict__ wsBoxes, const float* __restrict__ wsScores,
    const int* __restrict__ wsValid, const uint64_t* __restrict__ mask,
    float* __restrict__ out)
{
    const int n   = blockIdx.x;
    const int tid = threadIdx.x;

    __shared__ __align__(8) unsigned char invb[256];
    __shared__ unsigned int keepw32[64];
    __shared__ int sscan[256];

    unsigned int byte = 0xFFu;
    if (tid < PRE_N / 8) {
        byte = 0u;
        for (int q = 0; q < 8; ++q)
            byte |= (wsValid[n * PRE_N + tid * 8 + q] ? 0u : 1u) << q;
    }
    invb[tid] = (unsigned char)byte;
    __syncthreads();

    if (tid < 64) {
        unsigned int rem = ((const unsigned int*)invb)[tid];
        unsigned long long sbase =
            (unsigned long long)(const void*)(mask + (size_t)n * PRE_N * 32);
        unsigned int voff = (unsigned int)(tid * 4);
        int win_, m_, t_, lw_, kept_, cnt_;

        asm volatile(
            "s_waitcnt vmcnt(0) lgkmcnt(0)\n\t"
            "s_mov_b32 %[kept], 0\n\t"
            "s_mov_b32 %[lw], 0\n\t"
            ROW_A(SL) ROW_B(SL)
            "v_readlane_b32 %[t], %[rem], %[lw]\n\t"
            "s_mov_b32 %[win], %[t]\n\t"
            "s_mov_b32 %[cnt], 30\n\t"
            "Lnms_%=:\n\t"
            ROW_A(SS)
            SWIN
            ROW_B(SS)
            SWIN
            "s_cmp_ge_i32 %[kept], 0x3e8\n\t"
            "s_cbranch_scc1 Lend_%=\n\t"
            "s_sub_u32 %[cnt], %[cnt], 1\n\t"
            "s_cmp_lg_u32 %[cnt], 0\n\t"
            "s_cbranch_scc1 Lnms_%=\n\t"
            SS(64,0) SS(65,1) SS(66,2) SS(67,3) SS(68,4) SS(69,5) SS(70,6) SS(71,7)
            SS(72,8) SS(73,9) SS(74,10) SS(75,11) SS(76,12) SS(77,13) SS(78,14) SS(79,15)
            SN(80,16,63) SN(81,17,62) SN(82,18,61) SN(83,19,60)
            SN(84,20,59) SN(85,21,58) SN(86,22,57) SN(87,23,56)
            SN(88,24,55) SN(89,25,54) SN(90,26,53) SN(91,27,52)
            SN(92,28,51) SN(93,29,50) SN(94,30,49) SN(95,31,48)
            SWIN
            SN(96,0,47) SN(97,1,46) SN(98,2,45) SN(99,3,44)
            SN(100,4,43) SN(101,5,42) SN(102,6,41) SN(103,7,40)
            SN(104,8,39) SN(105,9,38) SN(106,10,37) SN(107,11,36)
            SN(108,12,35) SN(109,13,34) SN(110,14,33) SN(111,15,32)
            SN(112,16,31) SN(113,17,30) SN(114,18,29) SN(115,19,28)
            SN(116,20,27) SN(117,21,26) SN(118,22,25) SN(119,23,24)
            SN(120,24,23) SN(121,25,22) SN(122,26,21) SN(123,27,20)
            SN(124,28,19) SN(125,29,18) SN(126,30,17) SN(127,31,16)
            SWIN
            SN(64,0,15) SN(65,1,14) SN(66,2,13) SN(67,3,12)
            SN(68,4,11) SN(69,5,10) SN(70,6,9) SN(71,7,8)
            SN(72,8,7) SN(73,9,6) SN(74,10,5) SN(75,11,4)
            SN(76,12,3) SN(77,13,2) SN(78,14,1) SN(79,15,0)
            "Lend_%=:\n\t"
            "s_waitcnt vmcnt(0)\n\t"
            : [rem]"+v"(rem), [voff]"+v"(voff),
              [win]"=&s"(win_), [m]"=&s"(m_), [t]"=&s"(t_),
              [lw]"=&s"(lw_), [kept]"=&s"(kept_), [cnt]"=&s"(cnt_)
            : [sbase]"s"(sbase)
            : "scc", "vcc", "memory",
              "v64","v65","v66","v67","v68","v69","v70","v71",
              "v72","v73","v74","v75","v76","v77","v78","v79",
              "v80","v81","v82","v83","v84","v85","v86","v87",
              "v88","v89","v90","v91","v92","v93","v94","v95",
              "v96","v97","v98","v99","v100","v101","v102","v103",
              "v104","v105","v106","v107","v108","v109","v110","v111",
              "v112","v113","v114","v115","v116","v117","v118","v119",
              "v120","v121","v122","v123","v124","v125","v126","v127");

        keepw32[tid] = ~rem;
    }
    __syncthreads();

    int c[8]; const int base8 = tid * 8;
    int lsum = 0;
    for (int q = 0; q < 8; ++q) {
        const int i = base8 + q;
        c[q] = (i < PRE_N) ? (int)((keepw32[i >> 5] >> (i & 31)) & 1u) : 0;
        lsum += c[q];
    }
    sscan[tid] = lsum;
    __syncthreads();
    for (int off = 1; off < 256; off <<= 1) {
        int v = (tid >= off) ? sscan[tid - off] : 0;
        __syncthreads();
        sscan[tid] += v;
        __syncthreads();
    }
    const int excl  = sscan[tid] - lsum;
    const int total = sscan[255];

    float* ob  = out + n * POST_N * 4;
    float* osc = out + NIMG * POST_N * 4 + n * POST_N;
    float* ovd = out + NIMG * POST_N * 5 + n * POST_N;

    for (int i = tid; i < POST_N * 4; i += 256) ob[i] = 0.0f;
    for (int i = tid; i < POST_N; i += 256) osc[i] = 0.0f;
    const int lim = min(total, POST_N);
    for (int i = tid; i < POST_N; i += 256) ovd[i] = (i < lim) ? 1.0f : 0.0f;
    __syncthreads();

    int run = excl;
    for (int q = 0; q < 8; ++q) {
        const int i = base8 + q;
        if (i < PRE_N && c[q]) {
            if (run < POST_N) {
                float4 b = ((const float4*)wsBoxes)[n * PRE_N + i];
                ob[run * 4 + 0] = b.x;
                ob[run * 4 + 1] = b.y;
                ob[run * 4 + 2] = b.z;
                ob[run * 4 + 3] = b.w;
                osc[run] = wsScores[n * PRE_N + i];
            }
            run++;
        }
    }
}

extern "C" void kernel_launch(void* const* d_in, const int* in_sizes, int n_in,
                              void* d_out, int out_size, void* d_ws, size_t ws_size,
                              hipStream_t stream) {
    const float* obj  = (const float*)d_in[0];
    const float* breg = (const float*)d_in[1];
    // d_in[2] anchors unused (computed inline, exact in f32)
    float* ws        = (float*)d_ws;
    float* wsBoxes   = ws;                      // 64000 floats
    float* wsScores  = ws + 64000;              // 16000 floats
    int*   wsValid   = (int*)(ws + 80000);      // 16000 ints
    uint64_t* wsMask = (uint64_t*)(ws + 96000); // 8*2000*32 u64 = 4.096 MB

    topk_decode<<<NIMG, 1024, 0, stream>>>(obj, breg, wsBoxes, wsScores, wsValid);
    nms_mask<<<NIMG * 32, 512, 0, stream>>>(wsBoxes, wsMask);
    nms_scan_select<<<NIMG, 256, 0, stream>>>(wsBoxes, wsScores, wsValid, wsMask,
                                              (float*)d_out);
}